// Round 2
// baseline (509.632 us; speedup 1.0000x reference)
//
#include <hip/hip_runtime.h>
#include <stdint.h>

// ---------------- types / helpers ----------------
typedef short bf16x8 __attribute__((ext_vector_type(8)));
typedef float f32x4 __attribute__((ext_vector_type(4)));
typedef unsigned short u16;
typedef unsigned short u16x4 __attribute__((ext_vector_type(4)));

#define AS1 __attribute__((address_space(1)))
#define AS3 __attribute__((address_space(3)))

__device__ __forceinline__ void gll16(const void* g, void* l) {
  // async global->LDS, 16B per lane, LDS dest = wave-uniform base + lane*16
  __builtin_amdgcn_global_load_lds((const AS1 uint32_t*)g, (AS3 uint32_t*)l, 16, 0, 0);
}

__device__ __forceinline__ f32x4 mfma16(bf16x8 a, bf16x8 b, f32x4 c) {
  return __builtin_amdgcn_mfma_f32_16x16x32_bf16(a, b, c, 0, 0, 0);
}

__device__ __forceinline__ u16 f2bf(float f) {
  union { float f; uint32_t u; } c; c.f = f;
  uint32_t r = c.u + 0x7FFFu + ((c.u >> 16) & 1u);   // RNE
  return (u16)(r >> 16);
}
__device__ __forceinline__ float bf2f(u16 h) {
  union { uint32_t u; float f; } c; c.u = ((uint32_t)h) << 16; return c.f;
}

// ---------------- cast fp32 -> bf16 ----------------
__global__ __launch_bounds__(256) void k_cast(const float* __restrict__ in, u16* __restrict__ out) {
  int i = (blockIdx.x * 256 + threadIdx.x) * 4;
  float4 v = *(const float4*)(in + i);
  u16x4 r; r.x = f2bf(v.x); r.y = f2bf(v.y); r.z = f2bf(v.z); r.w = f2bf(v.w);
  *(u16x4*)(out + i) = r;
}

// ---------------- 4 weight transposes fp32 (1024x1024) -> bf16 transposed, one dispatch ----------------
__global__ __launch_bounds__(1024) void k_transpose4(
    const float* __restrict__ wq, const float* __restrict__ wk,
    const float* __restrict__ wv, const float* __restrict__ wo,
    u16* __restrict__ Wqkvt, u16* __restrict__ Wot) {
  __shared__ float t[32][33];
  const float* src; u16* dst;
  int z = blockIdx.z;
  if (z == 0)      { src = wq; dst = Wqkvt; }
  else if (z == 1) { src = wk; dst = Wqkvt + 1024 * 1024; }
  else if (z == 2) { src = wv; dst = Wqkvt + 2 * 1024 * 1024; }
  else             { src = wo; dst = Wot; }
  int tx = threadIdx.x, ty = threadIdx.y;
  t[ty][tx] = src[(size_t)(blockIdx.y * 32 + ty) * 1024 + blockIdx.x * 32 + tx];
  __syncthreads();
  dst[(size_t)(blockIdx.x * 32 + ty) * 1024 + blockIdx.y * 32 + tx] = f2bf(t[tx][ty]);
}

// ================= 256x256 / BK=64 / 8-wave / 8-phase pipelined main loop =================
// LDS 128 KiB: A dbuf [2][256][64] bf16 at 0, B dbuf [2][256][64] bf16 at 32768 (u16 units).
// Physical chunk swizzle: within a 64-col row (8 chunks of 8 bf16), phys = logical ^ (row&7).
// Staging: unit = 64 rows = 8KB = one gll16 per block (512 lanes x 16B), linear LDS dest,
// pre-swizzled global source. Per K-tile: A units 0..3, B units 0..3.
// Phase schedule per tile t (buf C=t&1), quadrant (MH,NH) = (p>>1, p&1):
//   ph0 reads A units {0,2}(C), stages A1,A3(t+1) -> !C
//   ph1 reads A units {0,2}(C), stages B0,B1(t+1) -> !C
//   ph2 reads A units {1,3}(C), stages B2,B3(t+1) -> !C and A0,A2(t+2) -> C  (units 0,2 of C
//        were last read in ph1; end-of-ph1 barrier makes the overwrite safe)
//   ph3 reads A units {1,3}(C)
//   end: s_waitcnt vmcnt(2)  (tile t+1 fully landed, A0,A2(t+2) stay in flight), s_barrier.
__device__ __forceinline__ void gemm256_loop(
    const u16* __restrict__ Ag, const u16* __restrict__ Bg,
    u16* lds, int m0, int n0, f32x4 (&acc)[8][4])
{
  const int tid = threadIdx.x, lane = tid & 63, w = tid >> 6;
  const int wm = w >> 2, wn = w & 3;
  const int l8 = lane >> 3, c7 = lane & 7;
  const int mm = lane & 15, quad = lane >> 4;
  const int ch0 = (quad ^ (mm & 7)) * 8;          // phys chunk for ks=0 (u16 offset)
  const int ch1 = ((quad ^ (mm & 7)) ^ 4) * 8;    // phys chunk for ks=1

  const u16* aSt = Ag + (size_t)(m0 + w * 8 + l8) * 1024 + (c7 ^ l8) * 8;
  const u16* bSt = Bg + (size_t)(n0 + w * 8 + l8) * 1024 + (c7 ^ l8) * 8;
  u16* ldsAw = lds + w * 512;
  u16* ldsBw = lds + 32768 + w * 512;
  const u16* aR0 = lds + (wm * 128 + mm) * 64 + ch0;
  const u16* aR1 = lds + (wm * 128 + mm) * 64 + ch1;
  const u16* bR0 = lds + 32768 + (wn * 64 + mm) * 64 + ch0;
  const u16* bR1 = lds + 32768 + (wn * 64 + mm) * 64 + ch1;

#define STA(q, kt, buf) gll16(aSt + (q) * 65536 + (kt) * 64, ldsAw + (buf) * 16384 + (q) * 4096)
#define STB(q, kt, buf) gll16(bSt + (q) * 65536 + (kt) * 64, ldsBw + (buf) * 16384 + (q) * 4096)

#pragma unroll
  for (int i = 0; i < 8; ++i)
#pragma unroll
    for (int j = 0; j < 4; ++j) acc[i][j] = (f32x4){0.f, 0.f, 0.f, 0.f};

  // prologue: all 8 units of tile 0 (buf 0), then A0,A2 of tile 1 (buf 1)
  STA(0, 0, 0); STA(1, 0, 0); STA(2, 0, 0); STA(3, 0, 0);
  STB(0, 0, 0); STB(1, 0, 0); STB(2, 0, 0); STB(3, 0, 0);
  STA(0, 1, 1); STA(2, 1, 1);
  asm volatile("s_waitcnt vmcnt(2)" ::: "memory");
  __builtin_amdgcn_s_barrier();

#define PH(C, MH, NH, STAGE) do {                                                        \
    bf16x8 af[4][2]; bf16x8 bf[2][2];                                                    \
    _Pragma("unroll")                                                                    \
    for (int i = 0; i < 4; ++i) {                                                        \
      af[i][0] = *(const bf16x8*)(aR0 + (C) * 16384 + ((MH) * 64 + i * 16) * 64);        \
      af[i][1] = *(const bf16x8*)(aR1 + (C) * 16384 + ((MH) * 64 + i * 16) * 64);        \
    }                                                                                    \
    _Pragma("unroll")                                                                    \
    for (int j = 0; j < 2; ++j) {                                                        \
      bf[j][0] = *(const bf16x8*)(bR0 + (C) * 16384 + ((NH) * 32 + j * 16) * 64);        \
      bf[j][1] = *(const bf16x8*)(bR1 + (C) * 16384 + ((NH) * 32 + j * 16) * 64);        \
    }                                                                                    \
    STAGE                                                                                \
    __builtin_amdgcn_s_barrier();                                                        \
    asm volatile("s_waitcnt lgkmcnt(0)" ::: "memory");                                   \
    __builtin_amdgcn_sched_barrier(0);                                                   \
    __builtin_amdgcn_s_setprio(1);                                                       \
    _Pragma("unroll")                                                                    \
    for (int ks = 0; ks < 2; ++ks)                                                       \
      _Pragma("unroll")                                                                  \
      for (int i = 0; i < 4; ++i)                                                        \
        _Pragma("unroll")                                                                \
        for (int j = 0; j < 2; ++j)                                                      \
          acc[(MH) * 4 + i][(NH) * 2 + j] =                                              \
              mfma16(af[i][ks], bf[j][ks], acc[(MH) * 4 + i][(NH) * 2 + j]);             \
    __builtin_amdgcn_s_setprio(0);                                                       \
  } while (0)

#pragma unroll 1
  for (int t = 0; t < 16; t += 2) {
    { // ---- tile t (buf 0) ----
      const int t1 = t + 1, t2 = t + 2;
      const bool s2 = t2 < 16;
      PH(0, 0, 0, { STA(1, t1, 1); STA(3, t1, 1); });
      __builtin_amdgcn_s_barrier();
      PH(0, 0, 1, { STB(0, t1, 1); STB(1, t1, 1); });
      __builtin_amdgcn_s_barrier();
      PH(0, 1, 0, { STB(2, t1, 1); STB(3, t1, 1); if (s2) { STA(0, t2, 0); STA(2, t2, 0); } });
      __builtin_amdgcn_s_barrier();
      PH(0, 1, 1, {});
      if (s2) asm volatile("s_waitcnt vmcnt(2)" ::: "memory");
      else    asm volatile("s_waitcnt vmcnt(0)" ::: "memory");
      __builtin_amdgcn_s_barrier();
    }
    { // ---- tile t+1 (buf 1) ----
      const int t2 = t + 2, t3 = t + 3;
      const bool s1 = t2 < 16, s2 = t3 < 16;
      PH(1, 0, 0, { if (s1) { STA(1, t2, 0); STA(3, t2, 0); } });
      __builtin_amdgcn_s_barrier();
      PH(1, 0, 1, { if (s1) { STB(0, t2, 0); STB(1, t2, 0); } });
      __builtin_amdgcn_s_barrier();
      PH(1, 1, 0, { if (s1) { STB(2, t2, 0); STB(3, t2, 0); } if (s2) { STA(0, t3, 1); STA(2, t3, 1); } });
      __builtin_amdgcn_s_barrier();
      PH(1, 1, 1, {});
      if (s2)      asm volatile("s_waitcnt vmcnt(2)" ::: "memory");
      else if (s1) asm volatile("s_waitcnt vmcnt(0)" ::: "memory");
      __builtin_amdgcn_s_barrier();
    }
  }
#undef PH
#undef STA
#undef STB
}

// ---------------- fused QKV GEMM: A[16384x1024] * Wqkvt[3072x1024]^T ----------------
// 256x256 tile, 512 threads, 128 KiB LDS, 1 block/CU.
__global__ __launch_bounds__(512, 2) void k_gemm_qkv(
    const u16* __restrict__ A, const u16* __restrict__ Bt,
    const float* __restrict__ bq, const float* __restrict__ bk, const float* __restrict__ bv,
    u16* __restrict__ Qb, u16* __restrict__ Kb, u16* __restrict__ Vbt, float* __restrict__ sumk)
{
  __shared__ __align__(16) u16 LDS[65536];   // 128 KiB
  const int m0 = blockIdx.y * 256, n0 = blockIdx.x * 256;
  f32x4 acc[8][4];
  gemm256_loop(A, Bt, LDS, m0, n0, acc);

  const int tid = threadIdx.x, lane = tid & 63, w = tid >> 6;
  const int wm = w >> 2, wn = w & 3;
  const int mm = lane & 15, quad = lane >> 4;
  const int sel = n0 >> 10;                   // 0=Q, 1=K, 2=V (uniform per block)
  const float* bias = sel == 0 ? bq : (sel == 1 ? bk : bv);
  const float scl = sel == 0 ? 0.125f : 1.0f;

#pragma unroll
  for (int nf = 0; nf < 4; ++nf) {
    int ngl = n0 + wn * 64 + nf * 16 + mm;
    int nq = ngl & 1023;
    int h = nq >> 6, d = nq & 63;
    float bval = bias[nq];
#pragma unroll
    for (int mf = 0; mf < 8; ++mf)
#pragma unroll
      for (int r = 0; r < 4; ++r) {
        int mg = m0 + wm * 128 + mf * 16 + quad * 4 + r;
        int b_ = mg >> 12, s = mg & 4095;
        float v = (acc[mf][nf][r] + bval) * scl;
        if (sel == 0)      Qb [((size_t)(b_ * 16 + h) * 4096 + s) * 64 + d] = f2bf(v);
        else if (sel == 1) Kb [((size_t)(b_ * 16 + h) * 4096 + s) * 64 + d] = f2bf(v);
        else               Vbt[((size_t)(b_ * 16 + h) * 64 + d) * 4096 + s] = f2bf(v);
      }
  }

  if (sel == 1) {
    // per-wave: wave (wm,wn) covers rows [m0+wm*128, +128) x cols [wn*64, +64)
    // -> exactly one sumk block (nb = m0/128 + wm) per wave, no cross-wave reduction.
#pragma unroll
    for (int nf = 0; nf < 4; ++nf) {
      float ssum = 0.f;
#pragma unroll
      for (int mf = 0; mf < 8; ++mf)
#pragma unroll
        for (int r = 0; r < 4; ++r) ssum += acc[mf][nf][r];
      ssum += __shfl_xor(ssum, 16);
      ssum += __shfl_xor(ssum, 32);            // sum over the 4 quads -> 128 rows
      if (quad == 0) {
        int colg = (n0 - 1024) + wn * 64 + nf * 16 + mm;
        int b_ = m0 >> 12, nb2 = ((m0 >> 7) & 31) + wm;
        sumk[(size_t)(b_ * 32 + nb2) * 1024 + colg] = ssum + 128.f * bias[colg];
      }
    }
  }
}

// ---------------- output GEMM: X[16384x1024] * Wot[1024x1024]^T + bo -> fp32 ----------------
__global__ __launch_bounds__(512, 2) void k_gemm_out(
    const u16* __restrict__ A, const u16* __restrict__ Bt,
    const float* __restrict__ bo, float* __restrict__ out)
{
  __shared__ __align__(16) u16 LDS[65536];   // 128 KiB
  const int m0 = blockIdx.y * 256, n0 = blockIdx.x * 256;
  f32x4 acc[8][4];
  gemm256_loop(A, Bt, LDS, m0, n0, acc);

  const int tid = threadIdx.x, lane = tid & 63, w = tid >> 6;
  const int wm = w >> 2, wn = w & 3;
  const int mm = lane & 15, quad = lane >> 4;
#pragma unroll
  for (int nf = 0; nf < 4; ++nf) {
    int ng = n0 + wn * 64 + nf * 16 + mm;
    float bval = bo[ng];
#pragma unroll
    for (int mf = 0; mf < 8; ++mf)
#pragma unroll
      for (int r = 0; r < 4; ++r) {
        int mg = m0 + wm * 128 + mf * 16 + quad * 4 + r;
        out[(size_t)mg * 1024 + ng] = acc[mf][nf][r] + bval;
      }
  }
}

// ---------------- sort logits: sumk[b][n][1024] @ w_sort[1024][32] + b_sort ----------------
__global__ __launch_bounds__(256) void k_sortmm(const float* __restrict__ sumk, const float* __restrict__ wsort,
                                                const float* __restrict__ bsort, float* __restrict__ so) {
  __shared__ float red[256];
  int n = blockIdx.x, b = blockIdx.y, t = threadIdx.x;
  int m = t & 31, kp = t >> 5;
  const float* row = sumk + (size_t)(b * 32 + n) * 1024;
  float acc = 0.f;
  for (int c = kp * 128; c < kp * 128 + 128; ++c) acc += row[c] * wsort[c * 32 + m];
  red[t] = acc;
  __syncthreads();
  if (t < 32) {
    float s = bsort[t];
#pragma unroll
    for (int q = 0; q < 8; ++q) s += red[q * 32 + t];
    so[(size_t)(b * 32 + n) * 32 + t] = s;
  }
}

// ---------------- Sinkhorn (5 iters) + clip + exp ----------------
__global__ __launch_bounds__(32) void k_sinkhorn(const float* __restrict__ so, float* __restrict__ perm) {
  __shared__ float A[32][33];
  int b = blockIdx.x, t = threadIdx.x;
  for (int i = 0; i < 32; ++i) A[i][t] = so[(size_t)(b * 32 + i) * 32 + t];
  __syncthreads();
  for (int it = 0; it < 5; ++it) {
    { // row LSE (axis=2)
      float mx = -1e30f;
      for (int j = 0; j < 32; ++j) mx = fmaxf(mx, A[t][j]);
      float s = 0.f;
      for (int j = 0; j < 32; ++j) s += __expf(A[t][j] - mx);
      float l = mx + __logf(s);
      for (int j = 0; j < 32; ++j) A[t][j] -= l;
    }
    __syncthreads();
    { // col LSE (axis=1)
      float mx = -1e30f;
      for (int j = 0; j < 32; ++j) mx = fmaxf(mx, A[j][t]);
      float s = 0.f;
      for (int j = 0; j < 32; ++j) s += __expf(A[j][t] - mx);
      float l = mx + __logf(s);
      for (int j = 0; j < 32; ++j) A[j][t] -= l;
    }
    __syncthreads();
  }
  for (int i = 0; i < 32; ++i)
    perm[(size_t)(b * 32 + i) * 32 + t] = __expf(fminf(fmaxf(A[i][t], -1.f), 1.f));
}

// ---------------- merged block mix: y<16 -> K-mix (h=y), y>=16 -> V-mix (h=y-16) ----------------
__global__ __launch_bounds__(256) void k_mix(
    const u16* __restrict__ Kb, const u16* __restrict__ Vbt, const float* __restrict__ perm,
    u16* __restrict__ Ksort, u16* __restrict__ Vsort)
{
  __shared__ float P[32][32];
  int b = blockIdx.z, y = blockIdx.y, xg = blockIdx.x;
  int tid = threadIdx.x;
#pragma unroll
  for (int i = 0; i < 4; ++i) {
    int idx = i * 256 + tid;
    P[idx >> 5][idx & 31] = perm[b * 1024 + idx];
  }
  __syncthreads();
  if (y < 16) {
    // K mix: Ksort[b][h][n][128s][64d] = sum_m perm[n][m] * K[b][h][m*128+s][d]
    int h = y;
    int ss = xg * 4 + (tid >> 6), d = tid & 63;
    const u16* Kg = Kb + (size_t)(b * 16 + h) * 262144;
    float xk[32];
#pragma unroll
    for (int m = 0; m < 32; ++m) xk[m] = bf2f(Kg[(size_t)(m * 128 + ss) * 64 + d]);
    size_t tbase = (size_t)((b * 16 + h) * 32) * 8192;
#pragma unroll
    for (int nn = 0; nn < 32; ++nn) {
      float sk = 0.f;
#pragma unroll
      for (int m4 = 0; m4 < 8; ++m4) {
        float4 pv = *(const float4*)&P[nn][m4 * 4];
        sk += pv.x * xk[m4 * 4 + 0] + pv.y * xk[m4 * 4 + 1] + pv.z * xk[m4 * 4 + 2] + pv.w * xk[m4 * 4 + 3];
      }
      Ksort[tbase + (size_t)nn * 8192 + ss * 64 + d] = f2bf(sk);
    }
  } else {
    // V mix (transposed): Vsort[b][h][n][64d][128s] from Vbt[b][h][d][s]
    int h = y - 16;
    int d = xg * 2 + (tid >> 7), ss = tid & 127;
    const u16* Vg = Vbt + ((size_t)(b * 16 + h) * 64 + d) * 4096;
    float xv[32];
#pragma unroll
    for (int m = 0; m < 32; ++m) xv[m] = bf2f(Vg[m * 128 + ss]);
    size_t tbase = (size_t)((b * 16 + h) * 32) * 8192;
#pragma unroll
    for (int nn = 0; nn < 32; ++nn) {
      float sv = 0.f;
#pragma unroll
      for (int m4 = 0; m4 < 8; ++m4) {
        float4 pv = *(const float4*)&P[nn][m4 * 4];
        sv += pv.x * xv[m4 * 4 + 0] + pv.y * xv[m4 * 4 + 1] + pv.z * xv[m4 * 4 + 2] + pv.w * xv[m4 * 4 + 3];
      }
      Vsort[tbase + (size_t)nn * 8192 + d * 128 + ss] = f2bf(sv);
    }
  }
}

// ---------------- attention per (b,n,h): softmax(Q Kcat^T) Vcat ----------------
__global__ __launch_bounds__(256, 2) void k_attn(
    const u16* __restrict__ Qb, const u16* __restrict__ Kb, const u16* __restrict__ Ksort,
    const u16* __restrict__ Vbt, const u16* __restrict__ Vsort, u16* __restrict__ X)
{
  __shared__ u16 Ks[16384];    // 256 kk x 64 d (swizzled); later overlaid by per-wave P
  __shared__ u16 Vlo[8192];    // 64 d x 128 kk (orig half, swizzled)
  __shared__ u16 Vhi[8192];    // 64 d x 128 kk (sorted half, swizzled)
  int tid = threadIdx.x, lane = tid & 63, w = tid >> 6;
  int n = blockIdx.x, h = blockIdx.y, b = blockIdx.z;
  size_t bh = (size_t)(b * 16 + h);
  size_t tileK = bh * 32 + n;

  { // stage Kcat rows: [0,128) from Kb, [128,256) from Ksort. chunk = 8 rows x 64 u16.
    int l8 = lane >> 3, sl8 = lane & 7;
    const u16* Korig = Kb + (bh * 4096 + (size_t)n * 128) * 64;
    const u16* Ksrt  = Ksort + tileK * 8192;
#pragma unroll
    for (int c = 0; c < 8; ++c) {
      int cc = w * 8 + c;
      int r = cc * 8 + l8;
      int pk = sl8 ^ (r & 7);
      const u16* src = (cc < 16) ? (Korig + (size_t)r * 64 + pk * 8)
                                 : (Ksrt + (size_t)(r - 128) * 64 + pk * 8);
      gll16(src, Ks + cc * 512);
    }
    // stage V panels: chunk = 4 d-rows x 128 u16.
    int l16 = lane >> 4, sl16 = lane & 15;
    const u16* Vorig = Vbt + bh * 262144 + (size_t)n * 128;
    const u16* Vsrt  = Vsort + tileK * 8192;
#pragma unroll
    for (int c = 0; c < 4; ++c) {
      int cc = w * 4 + c;
      int d = cc * 4 + l16;
      int pv = sl16 ^ (d & 15);
      gll16(Vorig + (size_t)d * 4096 + pv * 8, Vlo + cc * 512);
      gll16(Vsrt + (size_t)d * 128 + pv * 8, Vhi + cc * 512);
    }
  }

  int mm = lane & 15, quad = lane >> 4;
  bf16x8 qf[2][2];
  {
    size_t qrow = bh * 4096 + n * 128 + w * 32;
#pragma unroll
    for (int mt = 0; mt < 2; ++mt)
#pragma unroll
      for (int ks = 0; ks < 2; ++ks)
        qf[mt][ks] = *(const bf16x8*)(Qb + (qrow + mt * 16 + mm) * 64 + ks * 32 + quad * 8);
  }
  __syncthreads();

  // S = Qs @ Kcat^T  (wave w owns q rows [w*32, w*32+32))
  f32x4 S[2][16];
#pragma unroll
  for (int mt = 0; mt < 2; ++mt)
#pragma unroll
    for (int nt = 0; nt < 16; ++nt) S[mt][nt] = (f32x4){0.f, 0.f, 0.f, 0.f};
#pragma unroll
  for (int nt = 0; nt < 16; ++nt) {
    int kk = nt * 16 + mm;
#pragma unroll
    for (int ks = 0; ks < 2; ++ks) {
      int ch = (ks * 4 + quad) ^ (kk & 7);
      bf16x8 bk = *(const bf16x8*)(Ks + kk * 64 + ch * 8);
      S[0][nt] = mfma16(qf[0][ks], bk, S[0][nt]);
      S[1][nt] = mfma16(qf[1][ks], bk, S[1][nt]);
    }
  }

  // softmax over kk (C-layout: row = quad*4+r, col = mm across nt)
  float mx[2][4], ls[2][4];
#pragma unroll
  for (int mt = 0; mt < 2; ++mt)
#pragma unroll
    for (int r = 0; r < 4; ++r) {
      float v = S[mt][0][r];
#pragma unroll
      for (int nt = 1; nt < 16; ++nt) v = fmaxf(v, S[mt][nt][r]);
#pragma unroll
      for (int o = 1; o < 16; o <<= 1) v = fmaxf(v, __shfl_xor(v, o));
      mx[mt][r] = v;
    }
#pragma unroll
  for (int mt = 0; mt < 2; ++mt)
#pragma unroll
    for (int nt = 0; nt < 16; ++nt)
#pragma unroll
      for (int r = 0; r < 4; ++r)
        S[mt][nt][r] = __expf(S[mt][nt][r] - mx[mt][r]);
#pragma unroll
  for (int mt = 0; mt < 2; ++mt)
#pragma unroll
    for (int r = 0; r < 4; ++r) {
      float s = 0.f;
#pragma unroll
      for (int nt = 0; nt < 16; ++nt) s += S[mt][nt][r];
#pragma unroll
      for (int o = 1; o < 16; o <<= 1) s += __shfl_xor(s, o);
      ls[mt][r] = s;
    }

  __syncthreads();   // all waves done reading Ks before overlaying with P

  // PV in two kk halves; P (bf16) round-trips through per-wave LDS region over Ks
  u16* Pw = Ks + w * 4096;   // 32 q-rows x 128 kk per half (8KB per wave)
  f32x4 O[2][4];
#pragma unroll
  for (int mt = 0; mt < 2; ++mt)
#pragma unroll
    for (int dt = 0; dt < 4; ++dt) O[mt][dt] = (f32x4){0.f, 0.f, 0.f, 0.f};

#pragma unroll
  for (int half = 0; half < 2; ++half) {
    const u16* Vp = half == 0 ? Vlo : Vhi;
#pragma unroll
    for (int mt = 0; mt < 2; ++mt)
#pragma unroll
      for (int nt8 = 0; nt8 < 8; ++nt8) {
        int nt = half * 8 + nt8;
        int kkl = nt8 * 16 + mm;
#pragma unroll
        for (int r = 0; r < 4; ++r) {
          int q = mt * 16 + quad * 4 + r;
          int ch = (kkl >> 3) ^ (q & 15);
          Pw[q * 128 + ch * 8 + (kkl & 7)] = f2bf(S[mt][nt][r]);
        }
      }
#pragma unroll
    for (int ksl = 0; ksl < 4; ++ksl) {
      bf16x8 pa[2];
#pragma unroll
      for (int mt = 0; mt < 2; ++mt) {
        int q = mt * 16 + mm;
        int ch = (ksl * 4 + quad) ^ (q & 15);
        pa[mt] = *(const bf16x8*)(Pw + q * 128 + ch * 8);
      }
#pragma unroll
      for (int dt = 0; dt < 4; ++dt) {
        int d = dt * 16 + mm;
        int ch = (ksl * 4 + quad) ^ (d & 15);
        bf16x8 vb = *(const bf16x8*)(Vp + d * 128 + ch * 8);
        O[0][dt] = mfma16(pa[0], vb, O[0][dt]);
        O[1][dt] = mfma16(pa[1], vb, O[1][dt]);
      }
    }
  }

  // epilogue: normalize and write X[b*4096+s][h*64+d] (bf16)
#pragma unroll
  for (int mt = 0; mt < 2; ++mt)
#pragma unroll
    for (int dt = 0; dt < 4; ++dt)
#pragma unroll
      for (int r = 0; r < 4; ++r) {
        int q = w * 32 + mt * 16 + quad * 4 + r;
        float val = O[mt][dt][r] / ls[mt][r];
        size_t row = (size_t)b * 4096 + n * 128 + q;
        X[row * 1024 + h * 64 + dt * 16 + mm] = f2bf(val);
      }
}

// ---------------- launch ----------------
extern "C" void kernel_launch(void* const* d_in, const int* in_sizes, int n_in,
                              void* d_out, int out_size, void* d_ws, size_t ws_size,
                              hipStream_t stream) {
  const float* inq   = (const float*)d_in[0];
  const float* wq    = (const float*)d_in[1];
  const float* bq    = (const float*)d_in[2];
  const float* wk    = (const float*)d_in[3];
  const float* bk    = (const float*)d_in[4];
  const float* wv    = (const float*)d_in[5];
  const float* bv    = (const float*)d_in[6];
  const float* wsort = (const float*)d_in[7];
  const float* bsort = (const float*)d_in[8];
  const float* wo    = (const float*)d_in[9];
  const float* bo    = (const float*)d_in[10];
  float* out = (float*)d_out;

  char* ws = (char*)d_ws;
  size_t off = 0;
  auto alloc = [&](size_t bytes) { char* p = ws + off; off += (bytes + 255) & ~(size_t)255; return p; };
  u16*  Qb    = (u16*)alloc(33554432);   // [4][16][4096][64] bf16, pre-scaled 1/8
  u16*  Kb    = (u16*)alloc(33554432);   // K [4][16][4096][64]
  u16*  Vbt   = (u16*)alloc(33554432);   // V transposed [4][16][64][4096]
  u16*  Ksort = (u16*)alloc(33554432);   // sorted K [4][16][32][128][64]
  u16*  Vsort = (u16*)alloc(33554432);   // sorted V^T [4][16][32][64][128]
  u16*  Abf   = (u16*)alloc(33554432);   // bf16 input; later aliased as X
  u16*  Wqkvt = (u16*)alloc(6291456);    // [3072][1024] bf16 (B^T)
  u16*  Wot   = (u16*)alloc(2097152);    // [1024][1024] bf16 (B^T)
  float* sumk = (float*)alloc(524288);   // [4][32][1024]
  float* so   = (float*)alloc(16384);    // [4][32][32]
  float* perm = (float*)alloc(16384);    // [4][32][32]
  u16*  X = Abf;   // alias: attention output over Abf (dead after k_gemm_qkv)

  k_cast<<<16384, 256, 0, stream>>>(inq, Abf);
  k_transpose4<<<dim3(32, 32, 4), dim3(32, 32), 0, stream>>>(wq, wk, wv, wo, Wqkvt, Wot);
  k_gemm_qkv<<<dim3(12, 64), 512, 0, stream>>>(Abf, Wqkvt, bq, bk, bv, Qb, Kb, Vbt, sumk);
  k_sortmm<<<dim3(32, 4), 256, 0, stream>>>(sumk, wsort, bsort, so);
  k_sinkhorn<<<4, 32, 0, stream>>>(so, perm);
  k_mix<<<dim3(32, 32, 4), 256, 0, stream>>>(Kb, Vbt, perm, Ksort, Vsort);
  k_attn<<<dim3(32, 16, 4), 256, 0, stream>>>(Qb, Kb, Ksort, Vbt, Vsort, X);
  k_gemm_out<<<dim3(4, 64), 512, 0, stream>>>(X, Wot, bo, out);
}

// Round 3
// 495.318 us; speedup vs baseline: 1.0289x; 1.0289x over previous
//
#include <hip/hip_runtime.h>
#include <stdint.h>

// ---------------- types / helpers ----------------
typedef short bf16x8 __attribute__((ext_vector_type(8)));
typedef float f32x4 __attribute__((ext_vector_type(4)));
typedef unsigned short u16;
typedef unsigned short u16x4 __attribute__((ext_vector_type(4)));

#define AS1 __attribute__((address_space(1)))
#define AS3 __attribute__((address_space(3)))

__device__ __forceinline__ void gll16(const void* g, void* l) {
  // async global->LDS, 16B per lane, LDS dest = wave-uniform base + lane*16
  __builtin_amdgcn_global_load_lds((const AS1 uint32_t*)g, (AS3 uint32_t*)l, 16, 0, 0);
}

__device__ __forceinline__ f32x4 mfma16(bf16x8 a, bf16x8 b, f32x4 c) {
  return __builtin_amdgcn_mfma_f32_16x16x32_bf16(a, b, c, 0, 0, 0);
}

__device__ __forceinline__ u16 f2bf(float f) {
  union { float f; uint32_t u; } c; c.f = f;
  uint32_t r = c.u + 0x7FFFu + ((c.u >> 16) & 1u);   // RNE
  return (u16)(r >> 16);
}
__device__ __forceinline__ float bf2f(u16 h) {
  union { uint32_t u; float f; } c; c.u = ((uint32_t)h) << 16; return c.f;
}

// ---------------- cast fp32 -> bf16 ----------------
__global__ __launch_bounds__(256) void k_cast(const float* __restrict__ in, u16* __restrict__ out) {
  int i = (blockIdx.x * 256 + threadIdx.x) * 4;
  float4 v = *(const float4*)(in + i);
  u16x4 r; r.x = f2bf(v.x); r.y = f2bf(v.y); r.z = f2bf(v.z); r.w = f2bf(v.w);
  *(u16x4*)(out + i) = r;
}

// ---------------- 4 weight transposes fp32 (1024x1024) -> bf16 transposed, one dispatch ----------------
__global__ __launch_bounds__(1024) void k_transpose4(
    const float* __restrict__ wq, const float* __restrict__ wk,
    const float* __restrict__ wv, const float* __restrict__ wo,
    u16* __restrict__ Wqkvt, u16* __restrict__ Wot) {
  __shared__ float t[32][33];
  const float* src; u16* dst;
  int z = blockIdx.z;
  if (z == 0)      { src = wq; dst = Wqkvt; }
  else if (z == 1) { src = wk; dst = Wqkvt + 1024 * 1024; }
  else if (z == 2) { src = wv; dst = Wqkvt + 2 * 1024 * 1024; }
  else             { src = wo; dst = Wot; }
  int tx = threadIdx.x, ty = threadIdx.y;
  t[ty][tx] = src[(size_t)(blockIdx.y * 32 + ty) * 1024 + blockIdx.x * 32 + tx];
  __syncthreads();
  dst[(size_t)(blockIdx.x * 32 + ty) * 1024 + blockIdx.y * 32 + tx] = f2bf(t[tx][ty]);
}

// ================= 256x256 / BK=64 / 8-wave / 8-phase pipelined main loop =================
// LDS 128 KiB: A dbuf [2][256][64] bf16 at 0, B dbuf [2][256][64] bf16 at 32768 (u16 units).
// Physical chunk swizzle: within a 64-col row (8 chunks of 8 bf16), phys = logical ^ (row&7).
// Staging: unit = 64 rows = 8KB = one gll16 per block (512 lanes x 16B), linear LDS dest,
// pre-swizzled global source. Per K-tile: A units 0..3, B units 0..3.
//
// Quadrant order (0,0)->(0,1)->(1,1)->(1,0) with REGISTER-HELD fragments:
//   ph0: LDA(MH0)+LDB(NH0) [12 rd]; stage A1,A3(t+1)->!C
//   ph1: LDB(NH1) [4 rd], reuse af;  stage B0,B1(t+1)->!C
//   ph2: LDA(MH1) [8 rd], reuse bf;  stage B2,B3(t+1)->!C and A0,A2(t+2)->C
//        (A units 0,2 of C were read to REGISTERS in ph0; LDS overwrite is safe)
//   ph3: LDB(NH0) [4 rd], reuse af
//   end: s_waitcnt vmcnt(2) (tile t+1 fully landed, A0,A2(t+2) in flight), s_barrier.
// Per-tile LDS reads/wave: 28 x ds_read_b128 (was 48) -> LDS drain no longer the phase
// critical path vs 16 MFMA/phase.
__device__ __forceinline__ void gemm256_loop(
    const u16* __restrict__ Ag, const u16* __restrict__ Bg,
    u16* lds, int m0, int n0, f32x4 (&acc)[8][4])
{
  const int tid = threadIdx.x, lane = tid & 63, w = tid >> 6;
  const int wm = w >> 2, wn = w & 3;
  const int l8 = lane >> 3, c7 = lane & 7;
  const int mm = lane & 15, quad = lane >> 4;
  const int ch0 = (quad ^ (mm & 7)) * 8;          // phys chunk for ks=0 (u16 offset)
  const int ch1 = ((quad ^ (mm & 7)) ^ 4) * 8;    // phys chunk for ks=1

  const u16* aSt = Ag + (size_t)(m0 + w * 8 + l8) * 1024 + (c7 ^ l8) * 8;
  const u16* bSt = Bg + (size_t)(n0 + w * 8 + l8) * 1024 + (c7 ^ l8) * 8;
  u16* ldsAw = lds + w * 512;
  u16* ldsBw = lds + 32768 + w * 512;
  const u16* aR0 = lds + (wm * 128 + mm) * 64 + ch0;
  const u16* aR1 = lds + (wm * 128 + mm) * 64 + ch1;
  const u16* bR0 = lds + 32768 + (wn * 64 + mm) * 64 + ch0;
  const u16* bR1 = lds + 32768 + (wn * 64 + mm) * 64 + ch1;

#define STA(q, kt, buf) gll16(aSt + (q) * 65536 + (kt) * 64, ldsAw + (buf) * 16384 + (q) * 4096)
#define STB(q, kt, buf) gll16(bSt + (q) * 65536 + (kt) * 64, ldsBw + (buf) * 16384 + (q) * 4096)

#define LDA(C, MH) do {                                                                  \
    _Pragma("unroll")                                                                    \
    for (int i = 0; i < 4; ++i) {                                                        \
      af[i][0] = *(const bf16x8*)(aR0 + (C) * 16384 + ((MH) * 64 + i * 16) * 64);        \
      af[i][1] = *(const bf16x8*)(aR1 + (C) * 16384 + ((MH) * 64 + i * 16) * 64);        \
    }                                                                                    \
  } while (0)
#define LDB(C, NH) do {                                                                  \
    _Pragma("unroll")                                                                    \
    for (int j = 0; j < 2; ++j) {                                                        \
      bf[j][0] = *(const bf16x8*)(bR0 + (C) * 16384 + ((NH) * 32 + j * 16) * 64);        \
      bf[j][1] = *(const bf16x8*)(bR1 + (C) * 16384 + ((NH) * 32 + j * 16) * 64);        \
    }                                                                                    \
  } while (0)
#define MMQ(MH, NH) do {                                                                 \
    __builtin_amdgcn_s_barrier();                                                        \
    asm volatile("s_waitcnt lgkmcnt(0)" ::: "memory");                                   \
    __builtin_amdgcn_sched_barrier(0);                                                   \
    __builtin_amdgcn_s_setprio(1);                                                       \
    _Pragma("unroll")                                                                    \
    for (int ks = 0; ks < 2; ++ks)                                                       \
      _Pragma("unroll")                                                                  \
      for (int i = 0; i < 4; ++i)                                                        \
        _Pragma("unroll")                                                                \
        for (int j = 0; j < 2; ++j)                                                      \
          acc[(MH) * 4 + i][(NH) * 2 + j] =                                              \
              mfma16(af[i][ks], bf[j][ks], acc[(MH) * 4 + i][(NH) * 2 + j]);             \
    __builtin_amdgcn_s_setprio(0);                                                       \
  } while (0)

#pragma unroll
  for (int i = 0; i < 8; ++i)
#pragma unroll
    for (int j = 0; j < 4; ++j) acc[i][j] = (f32x4){0.f, 0.f, 0.f, 0.f};

  // prologue: all 8 units of tile 0 (buf 0), then A0,A2 of tile 1 (buf 1)
  STA(0, 0, 0); STA(1, 0, 0); STA(2, 0, 0); STA(3, 0, 0);
  STB(0, 0, 0); STB(1, 0, 0); STB(2, 0, 0); STB(3, 0, 0);
  STA(0, 1, 1); STA(2, 1, 1);
  asm volatile("s_waitcnt vmcnt(2)" ::: "memory");
  __builtin_amdgcn_s_barrier();

#pragma unroll 1
  for (int t = 0; t < 16; t += 2) {
    bf16x8 af[4][2]; bf16x8 bf[2][2];
    { // ---- tile t (buf 0) ----
      const int t1 = t + 1, t2 = t + 2;
      const bool s2 = t2 < 16;
      LDA(0, 0); LDB(0, 0); STA(1, t1, 1); STA(3, t1, 1);
      MMQ(0, 0);
      __builtin_amdgcn_s_barrier();
      LDB(0, 1); STB(0, t1, 1); STB(1, t1, 1);
      MMQ(0, 1);
      __builtin_amdgcn_s_barrier();
      LDA(0, 1); STB(2, t1, 1); STB(3, t1, 1); if (s2) { STA(0, t2, 0); STA(2, t2, 0); }
      MMQ(1, 1);
      __builtin_amdgcn_s_barrier();
      LDB(0, 0);
      MMQ(1, 0);
      if (s2) asm volatile("s_waitcnt vmcnt(2)" ::: "memory");
      else    asm volatile("s_waitcnt vmcnt(0)" ::: "memory");
      __builtin_amdgcn_s_barrier();
    }
    { // ---- tile t+1 (buf 1) ----
      const int t2 = t + 2, t3 = t + 3;
      const bool s1 = t2 < 16, s2 = t3 < 16;
      LDA(1, 0); LDB(1, 0); if (s1) { STA(1, t2, 0); STA(3, t2, 0); }
      MMQ(0, 0);
      __builtin_amdgcn_s_barrier();
      LDB(1, 1); if (s1) { STB(0, t2, 0); STB(1, t2, 0); }
      MMQ(0, 1);
      __builtin_amdgcn_s_barrier();
      LDA(1, 1); if (s1) { STB(2, t2, 0); STB(3, t2, 0); } if (s2) { STA(0, t3, 1); STA(2, t3, 1); }
      MMQ(1, 1);
      __builtin_amdgcn_s_barrier();
      LDB(1, 0);
      MMQ(1, 0);
      if (s2)      asm volatile("s_waitcnt vmcnt(2)" ::: "memory");
      else if (s1) asm volatile("s_waitcnt vmcnt(0)" ::: "memory");
      __builtin_amdgcn_s_barrier();
    }
  }
#undef MMQ
#undef LDA
#undef LDB
#undef STA
#undef STB
}

// ---------------- fused QKV GEMM: A[16384x1024] * Wqkvt[3072x1024]^T ----------------
// 256x256 tile, 512 threads, 128 KiB LDS, 1 block/CU.
__global__ __launch_bounds__(512, 2) void k_gemm_qkv(
    const u16* __restrict__ A, const u16* __restrict__ Bt,
    const float* __restrict__ bq, const float* __restrict__ bk, const float* __restrict__ bv,
    u16* __restrict__ Qb, u16* __restrict__ Kb, u16* __restrict__ Vbt, float* __restrict__ sumk)
{
  __shared__ __align__(16) u16 LDS[65536];   // 128 KiB
  const int m0 = blockIdx.y * 256, n0 = blockIdx.x * 256;
  f32x4 acc[8][4];
  gemm256_loop(A, Bt, LDS, m0, n0, acc);

  const int tid = threadIdx.x, lane = tid & 63, w = tid >> 6;
  const int wm = w >> 2, wn = w & 3;
  const int mm = lane & 15, quad = lane >> 4;
  const int sel = n0 >> 10;                   // 0=Q, 1=K, 2=V (uniform per block)
  const float* bias = sel == 0 ? bq : (sel == 1 ? bk : bv);
  const float scl = sel == 0 ? 0.125f : 1.0f;

#pragma unroll
  for (int nf = 0; nf < 4; ++nf) {
    int ngl = n0 + wn * 64 + nf * 16 + mm;
    int nq = ngl & 1023;
    int h = nq >> 6, d = nq & 63;
    float bval = bias[nq];
#pragma unroll
    for (int mf = 0; mf < 8; ++mf)
#pragma unroll
      for (int r = 0; r < 4; ++r) {
        int mg = m0 + wm * 128 + mf * 16 + quad * 4 + r;
        int b_ = mg >> 12, s = mg & 4095;
        float v = (acc[mf][nf][r] + bval) * scl;
        if (sel == 0)      Qb [((size_t)(b_ * 16 + h) * 4096 + s) * 64 + d] = f2bf(v);
        else if (sel == 1) Kb [((size_t)(b_ * 16 + h) * 4096 + s) * 64 + d] = f2bf(v);
        else               Vbt[((size_t)(b_ * 16 + h) * 64 + d) * 4096 + s] = f2bf(v);
      }
  }

  if (sel == 1) {
    // per-wave: wave (wm,wn) covers rows [m0+wm*128, +128) x cols [wn*64, +64)
    // -> exactly one sumk block (nb = m0/128 + wm) per wave, no cross-wave reduction.
#pragma unroll
    for (int nf = 0; nf < 4; ++nf) {
      float ssum = 0.f;
#pragma unroll
      for (int mf = 0; mf < 8; ++mf)
#pragma unroll
        for (int r = 0; r < 4; ++r) ssum += acc[mf][nf][r];
      ssum += __shfl_xor(ssum, 16);
      ssum += __shfl_xor(ssum, 32);            // sum over the 4 quads -> 128 rows
      if (quad == 0) {
        int colg = (n0 - 1024) + wn * 64 + nf * 16 + mm;
        int b_ = m0 >> 12, nb2 = ((m0 >> 7) & 31) + wm;
        sumk[(size_t)(b_ * 32 + nb2) * 1024 + colg] = ssum + 128.f * bias[colg];
      }
    }
  }
}

// ---------------- output GEMM: X[16384x1024] * Wot[1024x1024]^T + bo -> fp32 ----------------
__global__ __launch_bounds__(512, 2) void k_gemm_out(
    const u16* __restrict__ A, const u16* __restrict__ Bt,
    const float* __restrict__ bo, float* __restrict__ out)
{
  __shared__ __align__(16) u16 LDS[65536];   // 128 KiB
  const int m0 = blockIdx.y * 256, n0 = blockIdx.x * 256;
  f32x4 acc[8][4];
  gemm256_loop(A, Bt, LDS, m0, n0, acc);

  const int tid = threadIdx.x, lane = tid & 63, w = tid >> 6;
  const int wm = w >> 2, wn = w & 3;
  const int mm = lane & 15, quad = lane >> 4;
#pragma unroll
  for (int nf = 0; nf < 4; ++nf) {
    int ng = n0 + wn * 64 + nf * 16 + mm;
    float bval = bo[ng];
#pragma unroll
    for (int mf = 0; mf < 8; ++mf)
#pragma unroll
      for (int r = 0; r < 4; ++r) {
        int mg = m0 + wm * 128 + mf * 16 + quad * 4 + r;
        out[(size_t)mg * 1024 + ng] = acc[mf][nf][r] + bval;
      }
  }
}

// ---------------- sort logits: sumk[b][n][1024] @ w_sort[1024][32] + b_sort ----------------
__global__ __launch_bounds__(256) void k_sortmm(const float* __restrict__ sumk, const float* __restrict__ wsort,
                                                const float* __restrict__ bsort, float* __restrict__ so) {
  __shared__ float red[256];
  int n = blockIdx.x, b = blockIdx.y, t = threadIdx.x;
  int m = t & 31, kp = t >> 5;
  const float* row = sumk + (size_t)(b * 32 + n) * 1024;
  float acc = 0.f;
  for (int c = kp * 128; c < kp * 128 + 128; ++c) acc += row[c] * wsort[c * 32 + m];
  red[t] = acc;
  __syncthreads();
  if (t < 32) {
    float s = bsort[t];
#pragma unroll
    for (int q = 0; q < 8; ++q) s += red[q * 32 + t];
    so[(size_t)(b * 32 + n) * 32 + t] = s;
  }
}

// ---------------- Sinkhorn (5 iters) + clip + exp ----------------
__global__ __launch_bounds__(32) void k_sinkhorn(const float* __restrict__ so, float* __restrict__ perm) {
  __shared__ float A[32][33];
  int b = blockIdx.x, t = threadIdx.x;
  for (int i = 0; i < 32; ++i) A[i][t] = so[(size_t)(b * 32 + i) * 32 + t];
  __syncthreads();
  for (int it = 0; it < 5; ++it) {
    { // row LSE (axis=2)
      float mx = -1e30f;
      for (int j = 0; j < 32; ++j) mx = fmaxf(mx, A[t][j]);
      float s = 0.f;
      for (int j = 0; j < 32; ++j) s += __expf(A[t][j] - mx);
      float l = mx + __logf(s);
      for (int j = 0; j < 32; ++j) A[t][j] -= l;
    }
    __syncthreads();
    { // col LSE (axis=1)
      float mx = -1e30f;
      for (int j = 0; j < 32; ++j) mx = fmaxf(mx, A[j][t]);
      float s = 0.f;
      for (int j = 0; j < 32; ++j) s += __expf(A[j][t] - mx);
      float l = mx + __logf(s);
      for (int j = 0; j < 32; ++j) A[j][t] -= l;
    }
    __syncthreads();
  }
  for (int i = 0; i < 32; ++i)
    perm[(size_t)(b * 32 + i) * 32 + t] = __expf(fminf(fmaxf(A[i][t], -1.f), 1.f));
}

// ---------------- merged block mix: y<16 -> K-mix (h=y), y>=16 -> V-mix (h=y-16) ----------------
__global__ __launch_bounds__(256) void k_mix(
    const u16* __restrict__ Kb, const u16* __restrict__ Vbt, const float* __restrict__ perm,
    u16* __restrict__ Ksort, u16* __restrict__ Vsort)
{
  __shared__ float P[32][32];
  int b = blockIdx.z, y = blockIdx.y, xg = blockIdx.x;
  int tid = threadIdx.x;
#pragma unroll
  for (int i = 0; i < 4; ++i) {
    int idx = i * 256 + tid;
    P[idx >> 5][idx & 31] = perm[b * 1024 + idx];
  }
  __syncthreads();
  if (y < 16) {
    // K mix: Ksort[b][h][n][128s][64d] = sum_m perm[n][m] * K[b][h][m*128+s][d]
    int h = y;
    int ss = xg * 4 + (tid >> 6), d = tid & 63;
    const u16* Kg = Kb + (size_t)(b * 16 + h) * 262144;
    float xk[32];
#pragma unroll
    for (int m = 0; m < 32; ++m) xk[m] = bf2f(Kg[(size_t)(m * 128 + ss) * 64 + d]);
    size_t tbase = (size_t)((b * 16 + h) * 32) * 8192;
#pragma unroll
    for (int nn = 0; nn < 32; ++nn) {
      float sk = 0.f;
#pragma unroll
      for (int m4 = 0; m4 < 8; ++m4) {
        float4 pv = *(const float4*)&P[nn][m4 * 4];
        sk += pv.x * xk[m4 * 4 + 0] + pv.y * xk[m4 * 4 + 1] + pv.z * xk[m4 * 4 + 2] + pv.w * xk[m4 * 4 + 3];
      }
      Ksort[tbase + (size_t)nn * 8192 + ss * 64 + d] = f2bf(sk);
    }
  } else {
    // V mix (transposed): Vsort[b][h][n][64d][128s] from Vbt[b][h][d][s]
    int h = y - 16;
    int d = xg * 2 + (tid >> 7), ss = tid & 127;
    const u16* Vg = Vbt + ((size_t)(b * 16 + h) * 64 + d) * 4096;
    float xv[32];
#pragma unroll
    for (int m = 0; m < 32; ++m) xv[m] = bf2f(Vg[m * 128 + ss]);
    size_t tbase = (size_t)((b * 16 + h) * 32) * 8192;
#pragma unroll
    for (int nn = 0; nn < 32; ++nn) {
      float sv = 0.f;
#pragma unroll
      for (int m4 = 0; m4 < 8; ++m4) {
        float4 pv = *(const float4*)&P[nn][m4 * 4];
        sv += pv.x * xv[m4 * 4 + 0] + pv.y * xv[m4 * 4 + 1] + pv.z * xv[m4 * 4 + 2] + pv.w * xv[m4 * 4 + 3];
      }
      Vsort[tbase + (size_t)nn * 8192 + d * 128 + ss] = f2bf(sv);
    }
  }
}

// ---------------- attention per (b,n,h): softmax(Q Kcat^T) Vcat ----------------
__global__ __launch_bounds__(256, 2) void k_attn(
    const u16* __restrict__ Qb, const u16* __restrict__ Kb, const u16* __restrict__ Ksort,
    const u16* __restrict__ Vbt, const u16* __restrict__ Vsort, u16* __restrict__ X)
{
  __shared__ u16 Ks[16384];    // 256 kk x 64 d (swizzled); later overlaid by per-wave P
  __shared__ u16 Vlo[8192];    // 64 d x 128 kk (orig half, swizzled)
  __shared__ u16 Vhi[8192];    // 64 d x 128 kk (sorted half, swizzled)
  int tid = threadIdx.x, lane = tid & 63, w = tid >> 6;
  int n = blockIdx.x, h = blockIdx.y, b = blockIdx.z;
  size_t bh = (size_t)(b * 16 + h);
  size_t tileK = bh * 32 + n;

  { // stage Kcat rows: [0,128) from Kb, [128,256) from Ksort. chunk = 8 rows x 64 u16.
    int l8 = lane >> 3, sl8 = lane & 7;
    const u16* Korig = Kb + (bh * 4096 + (size_t)n * 128) * 64;
    const u16* Ksrt  = Ksort + tileK * 8192;
#pragma unroll
    for (int c = 0; c < 8; ++c) {
      int cc = w * 8 + c;
      int r = cc * 8 + l8;
      int pk = sl8 ^ (r & 7);
      const u16* src = (cc < 16) ? (Korig + (size_t)r * 64 + pk * 8)
                                 : (Ksrt + (size_t)(r - 128) * 64 + pk * 8);
      gll16(src, Ks + cc * 512);
    }
    // stage V panels: chunk = 4 d-rows x 128 u16.
    int l16 = lane >> 4, sl16 = lane & 15;
    const u16* Vorig = Vbt + bh * 262144 + (size_t)n * 128;
    const u16* Vsrt  = Vsort + tileK * 8192;
#pragma unroll
    for (int c = 0; c < 4; ++c) {
      int cc = w * 4 + c;
      int d = cc * 4 + l16;
      int pv = sl16 ^ (d & 15);
      gll16(Vorig + (size_t)d * 4096 + pv * 8, Vlo + cc * 512);
      gll16(Vsrt + (size_t)d * 128 + pv * 8, Vhi + cc * 512);
    }
  }

  int mm = lane & 15, quad = lane >> 4;
  bf16x8 qf[2][2];
  {
    size_t qrow = bh * 4096 + n * 128 + w * 32;
#pragma unroll
    for (int mt = 0; mt < 2; ++mt)
#pragma unroll
      for (int ks = 0; ks < 2; ++ks)
        qf[mt][ks] = *(const bf16x8*)(Qb + (qrow + mt * 16 + mm) * 64 + ks * 32 + quad * 8);
  }
  __syncthreads();

  // S = Qs @ Kcat^T  (wave w owns q rows [w*32, w*32+32))
  f32x4 S[2][16];
#pragma unroll
  for (int mt = 0; mt < 2; ++mt)
#pragma unroll
    for (int nt = 0; nt < 16; ++nt) S[mt][nt] = (f32x4){0.f, 0.f, 0.f, 0.f};
#pragma unroll
  for (int nt = 0; nt < 16; ++nt) {
    int kk = nt * 16 + mm;
#pragma unroll
    for (int ks = 0; ks < 2; ++ks) {
      int ch = (ks * 4 + quad) ^ (kk & 7);
      bf16x8 bk = *(const bf16x8*)(Ks + kk * 64 + ch * 8);
      S[0][nt] = mfma16(qf[0][ks], bk, S[0][nt]);
      S[1][nt] = mfma16(qf[1][ks], bk, S[1][nt]);
    }
  }

  // softmax over kk (C-layout: row = quad*4+r, col = mm across nt)
  float mx[2][4], ls[2][4];
#pragma unroll
  for (int mt = 0; mt < 2; ++mt)
#pragma unroll
    for (int r = 0; r < 4; ++r) {
      float v = S[mt][0][r];
#pragma unroll
      for (int nt = 1; nt < 16; ++nt) v = fmaxf(v, S[mt][nt][r]);
#pragma unroll
      for (int o = 1; o < 16; o <<= 1) v = fmaxf(v, __shfl_xor(v, o));
      mx[mt][r] = v;
    }
#pragma unroll
  for (int mt = 0; mt < 2; ++mt)
#pragma unroll
    for (int nt = 0; nt < 16; ++nt)
#pragma unroll
      for (int r = 0; r < 4; ++r)
        S[mt][nt][r] = __expf(S[mt][nt][r] - mx[mt][r]);
#pragma unroll
  for (int mt = 0; mt < 2; ++mt)
#pragma unroll
    for (int r = 0; r < 4; ++r) {
      float s = 0.f;
#pragma unroll
      for (int nt = 0; nt < 16; ++nt) s += S[mt][nt][r];
#pragma unroll
      for (int o = 1; o < 16; o <<= 1) s += __shfl_xor(s, o);
      ls[mt][r] = s;
    }

  __syncthreads();   // all waves done reading Ks before overlaying with P

  // PV in two kk halves; P (bf16) round-trips through per-wave LDS region over Ks
  u16* Pw = Ks + w * 4096;   // 32 q-rows x 128 kk per half (8KB per wave)
  f32x4 O[2][4];
#pragma unroll
  for (int mt = 0; mt < 2; ++mt)
#pragma unroll
    for (int dt = 0; dt < 4; ++dt) O[mt][dt] = (f32x4){0.f, 0.f, 0.f, 0.f};

#pragma unroll
  for (int half = 0; half < 2; ++half) {
    const u16* Vp = half == 0 ? Vlo : Vhi;
#pragma unroll
    for (int mt = 0; mt < 2; ++mt)
#pragma unroll
      for (int nt8 = 0; nt8 < 8; ++nt8) {
        int nt = half * 8 + nt8;
        int kkl = nt8 * 16 + mm;
#pragma unroll
        for (int r = 0; r < 4; ++r) {
          int q = mt * 16 + quad * 4 + r;
          int ch = (kkl >> 3) ^ (q & 15);
          Pw[q * 128 + ch * 8 + (kkl & 7)] = f2bf(S[mt][nt][r]);
        }
      }
#pragma unroll
    for (int ksl = 0; ksl < 4; ++ksl) {
      bf16x8 pa[2];
#pragma unroll
      for (int mt = 0; mt < 2; ++mt) {
        int q = mt * 16 + mm;
        int ch = (ksl * 4 + quad) ^ (q & 15);
        pa[mt] = *(const bf16x8*)(Pw + q * 128 + ch * 8);
      }
#pragma unroll
      for (int dt = 0; dt < 4; ++dt) {
        int d = dt * 16 + mm;
        int ch = (ksl * 4 + quad) ^ (d & 15);
        bf16x8 vb = *(const bf16x8*)(Vp + d * 128 + ch * 8);
        O[0][dt] = mfma16(pa[0], vb, O[0][dt]);
        O[1][dt] = mfma16(pa[1], vb, O[1][dt]);
      }
    }
  }

  // epilogue: normalize and write X[b*4096+s][h*64+d] (bf16)
#pragma unroll
  for (int mt = 0; mt < 2; ++mt)
#pragma unroll
    for (int dt = 0; dt < 4; ++dt)
#pragma unroll
      for (int r = 0; r < 4; ++r) {
        int q = w * 32 + mt * 16 + quad * 4 + r;
        float val = O[mt][dt][r] / ls[mt][r];
        size_t row = (size_t)b * 4096 + n * 128 + q;
        X[row * 1024 + h * 64 + dt * 16 + mm] = f2bf(val);
      }
}

// ---------------- launch ----------------
extern "C" void kernel_launch(void* const* d_in, const int* in_sizes, int n_in,
                              void* d_out, int out_size, void* d_ws, size_t ws_size,
                              hipStream_t stream) {
  const float* inq   = (const float*)d_in[0];
  const float* wq    = (const float*)d_in[1];
  const float* bq    = (const float*)d_in[2];
  const float* wk    = (const float*)d_in[3];
  const float* bk    = (const float*)d_in[4];
  const float* wv    = (const float*)d_in[5];
  const float* bv    = (const float*)d_in[6];
  const float* wsort = (const float*)d_in[7];
  const float* bsort = (const float*)d_in[8];
  const float* wo    = (const float*)d_in[9];
  const float* bo    = (const float*)d_in[10];
  float* out = (float*)d_out;

  char* ws = (char*)d_ws;
  size_t off = 0;
  auto alloc = [&](size_t bytes) { char* p = ws + off; off += (bytes + 255) & ~(size_t)255; return p; };
  u16*  Qb    = (u16*)alloc(33554432);   // [4][16][4096][64] bf16, pre-scaled 1/8
  u16*  Kb    = (u16*)alloc(33554432);   // K [4][16][4096][64]
  u16*  Vbt   = (u16*)alloc(33554432);   // V transposed [4][16][64][4096]
  u16*  Ksort = (u16*)alloc(33554432);   // sorted K [4][16][32][128][64]
  u16*  Vsort = (u16*)alloc(33554432);   // sorted V^T [4][16][32][64][128]
  u16*  Abf   = (u16*)alloc(33554432);   // bf16 input; later aliased as X
  u16*  Wqkvt = (u16*)alloc(6291456);    // [3072][1024] bf16 (B^T)
  u16*  Wot   = (u16*)alloc(2097152);    // [1024][1024] bf16 (B^T)
  float* sumk = (float*)alloc(524288);   // [4][32][1024]
  float* so   = (float*)alloc(16384);    // [4][32][32]
  float* perm = (float*)alloc(16384);    // [4][32][32]
  u16*  X = Abf;   // alias: attention output over Abf (dead after k_gemm_qkv)

  k_cast<<<16384, 256, 0, stream>>>(inq, Abf);
  k_transpose4<<<dim3(32, 32, 4), dim3(32, 32), 0, stream>>>(wq, wk, wv, wo, Wqkvt, Wot);
  k_gemm_qkv<<<dim3(12, 64), 512, 0, stream>>>(Abf, Wqkvt, bq, bk, bv, Qb, Kb, Vbt, sumk);
  k_sortmm<<<dim3(32, 4), 256, 0, stream>>>(sumk, wsort, bsort, so);
  k_sinkhorn<<<4, 32, 0, stream>>>(so, perm);
  k_mix<<<dim3(32, 32, 4), 256, 0, stream>>>(Kb, Vbt, perm, Ksort, Vsort);
  k_attn<<<dim3(32, 16, 4), 256, 0, stream>>>(Qb, Kb, Ksort, Vbt, Vsort, X);
  k_gemm_out<<<dim3(4, 64), 512, 0, stream>>>(X, Wot, bo, out);
}

// Round 4
// 446.879 us; speedup vs baseline: 1.1404x; 1.1084x over previous
//
#include <hip/hip_runtime.h>
#include <stdint.h>

// ---------------- types / helpers ----------------
typedef short bf16x8 __attribute__((ext_vector_type(8)));
typedef float f32x4 __attribute__((ext_vector_type(4)));
typedef unsigned short u16;
typedef unsigned short u16x4 __attribute__((ext_vector_type(4)));

#define AS1 __attribute__((address_space(1)))
#define AS3 __attribute__((address_space(3)))

__device__ __forceinline__ void gll16(const void* g, void* l) {
  // async global->LDS, 16B per lane, LDS dest = wave-uniform base + lane*16
  __builtin_amdgcn_global_load_lds((const AS1 uint32_t*)g, (AS3 uint32_t*)l, 16, 0, 0);
}

__device__ __forceinline__ f32x4 mfma16(bf16x8 a, bf16x8 b, f32x4 c) {
  return __builtin_amdgcn_mfma_f32_16x16x32_bf16(a, b, c, 0, 0, 0);
}

__device__ __forceinline__ u16 f2bf(float f) {
  union { float f; uint32_t u; } c; c.f = f;
  uint32_t r = c.u + 0x7FFFu + ((c.u >> 16) & 1u);   // RNE
  return (u16)(r >> 16);
}
__device__ __forceinline__ float bf2f(u16 h) {
  union { uint32_t u; float f; } c; c.u = ((uint32_t)h) << 16; return c.f;
}

// ---------------- cast fp32 -> bf16 ----------------
__global__ __launch_bounds__(256) void k_cast(const float* __restrict__ in, u16* __restrict__ out) {
  int i = (blockIdx.x * 256 + threadIdx.x) * 4;
  float4 v = *(const float4*)(in + i);
  u16x4 r; r.x = f2bf(v.x); r.y = f2bf(v.y); r.z = f2bf(v.z); r.w = f2bf(v.w);
  *(u16x4*)(out + i) = r;
}

// ---------------- 4 weight transposes fp32 (1024x1024) -> bf16 transposed, one dispatch ----------------
__global__ __launch_bounds__(1024) void k_transpose4(
    const float* __restrict__ wq, const float* __restrict__ wk,
    const float* __restrict__ wv, const float* __restrict__ wo,
    u16* __restrict__ Wqkvt, u16* __restrict__ Wot) {
  __shared__ float t[32][33];
  const float* src; u16* dst;
  int z = blockIdx.z;
  if (z == 0)      { src = wq; dst = Wqkvt; }
  else if (z == 1) { src = wk; dst = Wqkvt + 1024 * 1024; }
  else if (z == 2) { src = wv; dst = Wqkvt + 2 * 1024 * 1024; }
  else             { src = wo; dst = Wot; }
  int tx = threadIdx.x, ty = threadIdx.y;
  t[ty][tx] = src[(size_t)(blockIdx.y * 32 + ty) * 1024 + blockIdx.x * 32 + tx];
  __syncthreads();
  dst[(size_t)(blockIdx.x * 32 + ty) * 1024 + blockIdx.y * 32 + tx] = f2bf(t[tx][ty]);
}

// ================= 256x256 / BK=64 / 8-wave pipelined main loop =================
// LDS 128 KiB: A dbuf [2][256][64] bf16 at 0, B dbuf [2][256][64] bf16 at 32768 (u16 units).
// Chunk swizzle within a 64-col row (8 chunks of 8 bf16): phys = logical ^ (row&7).
// Staging unit = 64 rows = 8KB = one gll16 per 512-thread block, linear LDS dest,
// pre-swizzled global source. Per K-tile: A units 0..3, B units 0..3.
//
// DEEP uniform schedule (B gets 3-4 phases of flight, A gets 5-7):
//   ph0: LDA(C,0)+LDB(C,0) [12 rd]; stage B0,B1(t+1)->!C           ; MFMA(0,0)
//   ph1: LDB(C,1) [4 rd];           stage B2,B3(t+1)->!C, A0,A2(t+2)->C ; MFMA(0,1)
//   ph2: LDA(C,1) [8 rd];                                           ; MFMA(1,1)
//   ph3: LDB(C,0) [4 rd];           stage A1,A3(t+2)->C             ; MFMA(1,0)
//   end: vmcnt(4) (t+1 fully landed, A(t+2)x4 stay in flight); barrier.
// Hazards: A{0,2}(C) last read ph0 (held in reg) -> restage ph1 after ph0 barrier;
// A{1,3}(C) last read ph2 -> restage ph3; B(C) last read ph3 -> restaged next tile.
// Reads of restaged data are gated by the previous tile's vmcnt(4).
__device__ __forceinline__ void gemm256_loop(
    const u16* __restrict__ Ag, const u16* __restrict__ Bg,
    u16* lds, int m0, int n0, f32x4 (&acc)[8][4])
{
  const int tid = threadIdx.x, lane = tid & 63, w = tid >> 6;
  const int wm = w >> 2, wn = w & 3;
  const int l8 = lane >> 3, c7 = lane & 7;
  const int mm = lane & 15, quad = lane >> 4;
  const int ch0 = (quad ^ (mm & 7)) * 8;          // phys chunk for ks=0 (u16 offset)
  const int ch1 = ((quad ^ (mm & 7)) ^ 4) * 8;    // phys chunk for ks=1

  const u16* aSt = Ag + (size_t)(m0 + w * 8 + l8) * 1024 + (c7 ^ l8) * 8;
  const u16* bSt = Bg + (size_t)(n0 + w * 8 + l8) * 1024 + (c7 ^ l8) * 8;
  u16* ldsAw = lds + w * 512;
  u16* ldsBw = lds + 32768 + w * 512;
  const u16* aR0 = lds + (wm * 128 + mm) * 64 + ch0;
  const u16* aR1 = lds + (wm * 128 + mm) * 64 + ch1;
  const u16* bR0 = lds + 32768 + (wn * 64 + mm) * 64 + ch0;
  const u16* bR1 = lds + 32768 + (wn * 64 + mm) * 64 + ch1;

#define STA(q, kt, buf) gll16(aSt + (q) * 65536 + (kt) * 64, ldsAw + (buf) * 16384 + (q) * 4096)
#define STB(q, kt, buf) gll16(bSt + (q) * 65536 + (kt) * 64, ldsBw + (buf) * 16384 + (q) * 4096)

#define LDA(C, MH) do {                                                                  \
    _Pragma("unroll")                                                                    \
    for (int i = 0; i < 4; ++i) {                                                        \
      af[i][0] = *(const bf16x8*)(aR0 + (C) * 16384 + ((MH) * 64 + i * 16) * 64);        \
      af[i][1] = *(const bf16x8*)(aR1 + (C) * 16384 + ((MH) * 64 + i * 16) * 64);        \
    }                                                                                    \
  } while (0)
#define LDB(C, NH) do {                                                                  \
    _Pragma("unroll")                                                                    \
    for (int j = 0; j < 2; ++j) {                                                        \
      bf[j][0] = *(const bf16x8*)(bR0 + (C) * 16384 + ((NH) * 32 + j * 16) * 64);        \
      bf[j][1] = *(const bf16x8*)(bR1 + (C) * 16384 + ((NH) * 32 + j * 16) * 64);        \
    }                                                                                    \
  } while (0)
#define MMQ(MH, NH) do {                                                                 \
    __builtin_amdgcn_s_barrier();                                                        \
    asm volatile("s_waitcnt lgkmcnt(0)" ::: "memory");                                   \
    __builtin_amdgcn_sched_barrier(0);                                                   \
    __builtin_amdgcn_s_setprio(1);                                                       \
    _Pragma("unroll")                                                                    \
    for (int ks = 0; ks < 2; ++ks)                                                       \
      _Pragma("unroll")                                                                  \
      for (int i = 0; i < 4; ++i)                                                        \
        _Pragma("unroll")                                                                \
        for (int j = 0; j < 2; ++j)                                                      \
          acc[(MH) * 4 + i][(NH) * 2 + j] =                                              \
              mfma16(af[i][ks], bf[j][ks], acc[(MH) * 4 + i][(NH) * 2 + j]);             \
    __builtin_amdgcn_s_setprio(0);                                                       \
  } while (0)

// one K-tile: TT = tile index (runtime), C = LDS buffer (compile-time 0/1)
#define TILE(TT, C) do {                                                                 \
    const int t1 = (TT) + 1, t2 = (TT) + 2;                                              \
    const bool sB = t1 < 16, sA = t2 < 16;                                               \
    LDA(C, 0); LDB(C, 0); if (sB) { STB(0, t1, 1 - (C)); STB(1, t1, 1 - (C)); }          \
    MMQ(0, 0);                                                                           \
    __builtin_amdgcn_s_barrier();                                                        \
    LDB(C, 1); if (sB) { STB(2, t1, 1 - (C)); STB(3, t1, 1 - (C)); }                     \
    if (sA) { STA(0, t2, C); STA(2, t2, C); }                                            \
    MMQ(0, 1);                                                                           \
    __builtin_amdgcn_s_barrier();                                                        \
    LDA(C, 1);                                                                           \
    MMQ(1, 1);                                                                           \
    __builtin_amdgcn_s_barrier();                                                        \
    LDB(C, 0); if (sA) { STA(1, t2, C); STA(3, t2, C); }                                 \
    MMQ(1, 0);                                                                           \
    if ((TT) < 14)       asm volatile("s_waitcnt vmcnt(4)" ::: "memory");                \
    else if ((TT) == 14) asm volatile("s_waitcnt vmcnt(0)" ::: "memory");                \
    __builtin_amdgcn_s_barrier();                                                        \
  } while (0)

#pragma unroll
  for (int i = 0; i < 8; ++i)
#pragma unroll
    for (int j = 0; j < 4; ++j) acc[i][j] = (f32x4){0.f, 0.f, 0.f, 0.f};

  // prologue: A,B of tile 0 -> buf0; all of A of tile 1 -> buf1 (stays in flight)
  STA(0, 0, 0); STA(1, 0, 0); STA(2, 0, 0); STA(3, 0, 0);
  STB(0, 0, 0); STB(1, 0, 0); STB(2, 0, 0); STB(3, 0, 0);
  STA(0, 1, 1); STA(1, 1, 1); STA(2, 1, 1); STA(3, 1, 1);
  asm volatile("s_waitcnt vmcnt(4)" ::: "memory");
  __builtin_amdgcn_s_barrier();

#pragma unroll 1
  for (int t = 0; t < 16; t += 2) {
    bf16x8 af[4][2]; bf16x8 bf[2][2];
    TILE(t, 0);
    TILE(t + 1, 1);
  }
#undef TILE
#undef MMQ
#undef LDA
#undef LDB
#undef STA
#undef STB
}

// ---------------- fused QKV GEMM: A[16384x1024] * Wqkvt[3072x1024]^T ----------------
// 256x256 tile, 512 threads, 128 KiB LDS, 1 block/CU. XCD-chunked block swizzle (768=8*96).
__global__ __launch_bounds__(512, 2) void k_gemm_qkv(
    const u16* __restrict__ A, const u16* __restrict__ Bt,
    const float* __restrict__ bq, const float* __restrict__ bk, const float* __restrict__ bv,
    u16* __restrict__ Qb, u16* __restrict__ Kb, u16* __restrict__ Vbt, float* __restrict__ sumk)
{
  __shared__ __align__(16) u16 LDS[65536];   // 128 KiB
  int lin = blockIdx.x + 12 * blockIdx.y;          // 0..767
  int nb = (lin & 7) * 96 + (lin >> 3);            // bijective XCD chunking
  const int m0 = (nb / 12) * 256, n0 = (nb % 12) * 256;
  f32x4 acc[8][4];
  gemm256_loop(A, Bt, LDS, m0, n0, acc);

  const int tid = threadIdx.x, lane = tid & 63, w = tid >> 6;
  const int wm = w >> 2, wn = w & 3;
  const int mm = lane & 15, quad = lane >> 4;
  const int sel = n0 >> 10;                   // 0=Q, 1=K, 2=V (uniform per block)
  const float* bias = sel == 0 ? bq : (sel == 1 ? bk : bv);

  if (sel == 2) {
    // ---- V epilogue: per-wave LDS transpose, then coalesced d-major 8B stores ----
    // wave (wm,wn) owns head h_w = ((n0&1023)+wn*64)>>6, rows s in [m0+wm*128,+128).
    // LDS region: 16KB/wave = [64 d][128 s] bf16, chunk(4xu16) swizz c' = c ^ (d&15).
    u16* W = LDS + w * 8192;
#pragma unroll
    for (int nf = 0; nf < 4; ++nf) {
      int d = nf * 16 + mm;
      float bval = bias[((n0 & 1023) + wn * 64 + nf * 16 + mm)];
#pragma unroll
      for (int mf = 0; mf < 8; ++mf) {
        int c = mf * 4 + quad;
        u16x4 pk;
        pk.x = f2bf(acc[mf][nf][0] + bval);
        pk.y = f2bf(acc[mf][nf][1] + bval);
        pk.z = f2bf(acc[mf][nf][2] + bval);
        pk.w = f2bf(acc[mf][nf][3] + bval);
        *(u16x4*)(W + d * 128 + (c ^ (d & 15)) * 4) = pk;
      }
    }
    asm volatile("s_waitcnt lgkmcnt(0)" ::: "memory");
    int h_w = ((n0 & 1023) >> 6) + wn;
    int b_ = m0 >> 12;
    int c = lane & 31, dpar = lane >> 5;
    size_t gbase = ((size_t)(b_ * 16 + h_w) * 64) * 4096 + (m0 & 4095) + wm * 128 + c * 4;
#pragma unroll
    for (int dd = 0; dd < 32; ++dd) {
      int d = dd * 2 + dpar;
      u16x4 v = *(const u16x4*)(W + d * 128 + (c ^ (d & 15)) * 4);
      *(u16x4*)(Vbt + gbase + (size_t)d * 4096) = v;
    }
    return;
  }

  const float scl = sel == 0 ? 0.125f : 1.0f;
#pragma unroll
  for (int nf = 0; nf < 4; ++nf) {
    int ngl = n0 + wn * 64 + nf * 16 + mm;
    int nq = ngl & 1023;
    int h = nq >> 6, d = nq & 63;
    float bval = bias[nq];
#pragma unroll
    for (int mf = 0; mf < 8; ++mf)
#pragma unroll
      for (int r = 0; r < 4; ++r) {
        int mg = m0 + wm * 128 + mf * 16 + quad * 4 + r;
        int b_ = mg >> 12, s = mg & 4095;
        float v = (acc[mf][nf][r] + bval) * scl;
        if (sel == 0) Qb[((size_t)(b_ * 16 + h) * 4096 + s) * 64 + d] = f2bf(v);
        else          Kb[((size_t)(b_ * 16 + h) * 4096 + s) * 64 + d] = f2bf(v);
      }
  }

  if (sel == 1) {
    // per-wave: wave (wm,wn) covers rows [m0+wm*128, +128) x cols [wn*64, +64)
    // -> exactly one sumk block (nb = m0/128 + wm) per wave, no cross-wave reduction.
#pragma unroll
    for (int nf = 0; nf < 4; ++nf) {
      float ssum = 0.f;
#pragma unroll
      for (int mf = 0; mf < 8; ++mf)
#pragma unroll
        for (int r = 0; r < 4; ++r) ssum += acc[mf][nf][r];
      ssum += __shfl_xor(ssum, 16);
      ssum += __shfl_xor(ssum, 32);            // sum over the 4 quads -> 128 rows
      if (quad == 0) {
        int colg = (n0 - 1024) + wn * 64 + nf * 16 + mm;
        int b_ = m0 >> 12, nb2 = ((m0 >> 7) & 31) + wm;
        sumk[(size_t)(b_ * 32 + nb2) * 1024 + colg] = ssum + 128.f * bias[colg];
      }
    }
  }
}

// ---------------- output GEMM: X[16384x1024] * Wot[1024x1024]^T + bo -> fp32 ----------------
__global__ __launch_bounds__(512, 2) void k_gemm_out(
    const u16* __restrict__ A, const u16* __restrict__ Bt,
    const float* __restrict__ bo, float* __restrict__ out)
{
  __shared__ __align__(16) u16 LDS[65536];   // 128 KiB
  int lin = blockIdx.x + 4 * blockIdx.y;           // 0..255
  int nb = (lin & 7) * 32 + (lin >> 3);            // bijective XCD chunking
  const int m0 = (nb / 4) * 256, n0 = (nb % 4) * 256;
  f32x4 acc[8][4];
  gemm256_loop(A, Bt, LDS, m0, n0, acc);

  const int tid = threadIdx.x, lane = tid & 63, w = tid >> 6;
  const int wm = w >> 2, wn = w & 3;
  const int mm = lane & 15, quad = lane >> 4;
#pragma unroll
  for (int nf = 0; nf < 4; ++nf) {
    int ng = n0 + wn * 64 + nf * 16 + mm;
    float bval = bo[ng];
#pragma unroll
    for (int mf = 0; mf < 8; ++mf)
#pragma unroll
      for (int r = 0; r < 4; ++r) {
        int mg = m0 + wm * 128 + mf * 16 + quad * 4 + r;
        out[(size_t)mg * 1024 + ng] = acc[mf][nf][r] + bval;
      }
  }
}

// ---------------- sort logits: sumk[b][n][1024] @ w_sort[1024][32] + b_sort ----------------
__global__ __launch_bounds__(256) void k_sortmm(const float* __restrict__ sumk, const float* __restrict__ wsort,
                                                const float* __restrict__ bsort, float* __restrict__ so) {
  __shared__ float red[256];
  int n = blockIdx.x, b = blockIdx.y, t = threadIdx.x;
  int m = t & 31, kp = t >> 5;
  const float* row = sumk + (size_t)(b * 32 + n) * 1024;
  float acc = 0.f;
  for (int c = kp * 128; c < kp * 128 + 128; ++c) acc += row[c] * wsort[c * 32 + m];
  red[t] = acc;
  __syncthreads();
  if (t < 32) {
    float s = bsort[t];
#pragma unroll
    for (int q = 0; q < 8; ++q) s += red[q * 32 + t];
    so[(size_t)(b * 32 + n) * 32 + t] = s;
  }
}

// ---------------- Sinkhorn (5 iters) + clip + exp ----------------
__global__ __launch_bounds__(32) void k_sinkhorn(const float* __restrict__ so, float* __restrict__ perm) {
  __shared__ float A[32][33];
  int b = blockIdx.x, t = threadIdx.x;
  for (int i = 0; i < 32; ++i) A[i][t] = so[(size_t)(b * 32 + i) * 32 + t];
  __syncthreads();
  for (int it = 0; it < 5; ++it) {
    { // row LSE (axis=2)
      float mx = -1e30f;
      for (int j = 0; j < 32; ++j) mx = fmaxf(mx, A[t][j]);
      float s = 0.f;
      for (int j = 0; j < 32; ++j) s += __expf(A[t][j] - mx);
      float l = mx + __logf(s);
      for (int j = 0; j < 32; ++j) A[t][j] -= l;
    }
    __syncthreads();
    { // col LSE (axis=1)
      float mx = -1e30f;
      for (int j = 0; j < 32; ++j) mx = fmaxf(mx, A[j][t]);
      float s = 0.f;
      for (int j = 0; j < 32; ++j) s += __expf(A[j][t] - mx);
      float l = mx + __logf(s);
      for (int j = 0; j < 32; ++j) A[j][t] -= l;
    }
    __syncthreads();
  }
  for (int i = 0; i < 32; ++i)
    perm[(size_t)(b * 32 + i) * 32 + t] = __expf(fminf(fmaxf(A[i][t], -1.f), 1.f));
}

// ---------------- merged block mix: y<16 -> K-mix (h=y), y>=16 -> V-mix (h=y-16) ----------------
__global__ __launch_bounds__(256) void k_mix(
    const u16* __restrict__ Kb, const u16* __restrict__ Vbt, const float* __restrict__ perm,
    u16* __restrict__ Ksort, u16* __restrict__ Vsort)
{
  __shared__ float P[32][32];
  int b = blockIdx.z, y = blockIdx.y, xg = blockIdx.x;
  int tid = threadIdx.x;
#pragma unroll
  for (int i = 0; i < 4; ++i) {
    int idx = i * 256 + tid;
    P[idx >> 5][idx & 31] = perm[b * 1024 + idx];
  }
  __syncthreads();
  if (y < 16) {
    // K mix: Ksort[b][h][n][128s][64d] = sum_m perm[n][m] * K[b][h][m*128+s][d]
    int h = y;
    int ss = xg * 4 + (tid >> 6), d = tid & 63;
    const u16* Kg = Kb + (size_t)(b * 16 + h) * 262144;
    float xk[32];
#pragma unroll
    for (int m = 0; m < 32; ++m) xk[m] = bf2f(Kg[(size_t)(m * 128 + ss) * 64 + d]);
    size_t tbase = (size_t)((b * 16 + h) * 32) * 8192;
#pragma unroll
    for (int nn = 0; nn < 32; ++nn) {
      float sk = 0.f;
#pragma unroll
      for (int m4 = 0; m4 < 8; ++m4) {
        float4 pv = *(const float4*)&P[nn][m4 * 4];
        sk += pv.x * xk[m4 * 4 + 0] + pv.y * xk[m4 * 4 + 1] + pv.z * xk[m4 * 4 + 2] + pv.w * xk[m4 * 4 + 3];
      }
      Ksort[tbase + (size_t)nn * 8192 + ss * 64 + d] = f2bf(sk);
    }
  } else {
    // V mix (transposed): Vsort[b][h][n][64d][128s] from Vbt[b][h][d][s]
    int h = y - 16;
    int d = xg * 2 + (tid >> 7), ss = tid & 127;
    const u16* Vg = Vbt + ((size_t)(b * 16 + h) * 64 + d) * 4096;
    float xv[32];
#pragma unroll
    for (int m = 0; m < 32; ++m) xv[m] = bf2f(Vg[m * 128 + ss]);
    size_t tbase = (size_t)((b * 16 + h) * 32) * 8192;
#pragma unroll
    for (int nn = 0; nn < 32; ++nn) {
      float sv = 0.f;
#pragma unroll
      for (int m4 = 0; m4 < 8; ++m4) {
        float4 pv = *(const float4*)&P[nn][m4 * 4];
        sv += pv.x * xv[m4 * 4 + 0] + pv.y * xv[m4 * 4 + 1] + pv.z * xv[m4 * 4 + 2] + pv.w * xv[m4 * 4 + 3];
      }
      Vsort[tbase + (size_t)nn * 8192 + d * 128 + ss] = f2bf(sv);
    }
  }
}

// ---------------- attention per (b,n,h): softmax(Q Kcat^T) Vcat ----------------
__global__ __launch_bounds__(256, 2) void k_attn(
    const u16* __restrict__ Qb, const u16* __restrict__ Kb, const u16* __restrict__ Ksort,
    const u16* __restrict__ Vbt, const u16* __restrict__ Vsort, u16* __restrict__ X)
{
  __shared__ u16 Ks[16384];    // 256 kk x 64 d (swizzled); later overlaid by per-wave P
  __shared__ u16 Vlo[8192];    // 64 d x 128 kk (orig half, swizzled)
  __shared__ u16 Vhi[8192];    // 64 d x 128 kk (sorted half, swizzled)
  int tid = threadIdx.x, lane = tid & 63, w = tid >> 6;
  int n = blockIdx.x, h = blockIdx.y, b = blockIdx.z;
  size_t bh = (size_t)(b * 16 + h);
  size_t tileK = bh * 32 + n;

  { // stage Kcat rows: [0,128) from Kb, [128,256) from Ksort. chunk = 8 rows x 64 u16.
    int l8 = lane >> 3, sl8 = lane & 7;
    const u16* Korig = Kb + (bh * 4096 + (size_t)n * 128) * 64;
    const u16* Ksrt  = Ksort + tileK * 8192;
#pragma unroll
    for (int c = 0; c < 8; ++c) {
      int cc = w * 8 + c;
      int r = cc * 8 + l8;
      int pk = sl8 ^ (r & 7);
      const u16* src = (cc < 16) ? (Korig + (size_t)r * 64 + pk * 8)
                                 : (Ksrt + (size_t)(r - 128) * 64 + pk * 8);
      gll16(src, Ks + cc * 512);
    }
    // stage V panels: chunk = 4 d-rows x 128 u16.
    int l16 = lane >> 4, sl16 = lane & 15;
    const u16* Vorig = Vbt + bh * 262144 + (size_t)n * 128;
    const u16* Vsrt  = Vsort + tileK * 8192;
#pragma unroll
    for (int c = 0; c < 4; ++c) {
      int cc = w * 4 + c;
      int d = cc * 4 + l16;
      int pv = sl16 ^ (d & 15);
      gll16(Vorig + (size_t)d * 4096 + pv * 8, Vlo + cc * 512);
      gll16(Vsrt + (size_t)d * 128 + pv * 8, Vhi + cc * 512);
    }
  }

  int mm = lane & 15, quad = lane >> 4;
  bf16x8 qf[2][2];
  {
    size_t qrow = bh * 4096 + n * 128 + w * 32;
#pragma unroll
    for (int mt = 0; mt < 2; ++mt)
#pragma unroll
      for (int ks = 0; ks < 2; ++ks)
        qf[mt][ks] = *(const bf16x8*)(Qb + (qrow + mt * 16 + mm) * 64 + ks * 32 + quad * 8);
  }
  __syncthreads();

  // S = Qs @ Kcat^T  (wave w owns q rows [w*32, w*32+32))
  f32x4 S[2][16];
#pragma unroll
  for (int mt = 0; mt < 2; ++mt)
#pragma unroll
    for (int nt = 0; nt < 16; ++nt) S[mt][nt] = (f32x4){0.f, 0.f, 0.f, 0.f};
#pragma unroll
  for (int nt = 0; nt < 16; ++nt) {
    int kk = nt * 16 + mm;
#pragma unroll
    for (int ks = 0; ks < 2; ++ks) {
      int ch = (ks * 4 + quad) ^ (kk & 7);
      bf16x8 bk = *(const bf16x8*)(Ks + kk * 64 + ch * 8);
      S[0][nt] = mfma16(qf[0][ks], bk, S[0][nt]);
      S[1][nt] = mfma16(qf[1][ks], bk, S[1][nt]);
    }
  }

  // softmax over kk (C-layout: row = quad*4+r, col = mm across nt)
  float mx[2][4], ls[2][4];
#pragma unroll
  for (int mt = 0; mt < 2; ++mt)
#pragma unroll
    for (int r = 0; r < 4; ++r) {
      float v = S[mt][0][r];
#pragma unroll
      for (int nt = 1; nt < 16; ++nt) v = fmaxf(v, S[mt][nt][r]);
#pragma unroll
      for (int o = 1; o < 16; o <<= 1) v = fmaxf(v, __shfl_xor(v, o));
      mx[mt][r] = v;
    }
#pragma unroll
  for (int mt = 0; mt < 2; ++mt)
#pragma unroll
    for (int nt = 0; nt < 16; ++nt)
#pragma unroll
      for (int r = 0; r < 4; ++r)
        S[mt][nt][r] = __expf(S[mt][nt][r] - mx[mt][r]);
#pragma unroll
  for (int mt = 0; mt < 2; ++mt)
#pragma unroll
    for (int r = 0; r < 4; ++r) {
      float s = 0.f;
#pragma unroll
      for (int nt = 0; nt < 16; ++nt) s += S[mt][nt][r];
#pragma unroll
      for (int o = 1; o < 16; o <<= 1) s += __shfl_xor(s, o);
      ls[mt][r] = s;
    }

  __syncthreads();   // all waves done reading Ks before overlaying with P

  // PV in two kk halves; P (bf16) round-trips through per-wave LDS region over Ks
  u16* Pw = Ks + w * 4096;   // 32 q-rows x 128 kk per half (8KB per wave)
  f32x4 O[2][4];
#pragma unroll
  for (int mt = 0; mt < 2; ++mt)
#pragma unroll
    for (int dt = 0; dt < 4; ++dt) O[mt][dt] = (f32x4){0.f, 0.f, 0.f, 0.f};

#pragma unroll
  for (int half = 0; half < 2; ++half) {
    const u16* Vp = half == 0 ? Vlo : Vhi;
#pragma unroll
    for (int mt = 0; mt < 2; ++mt)
#pragma unroll
      for (int nt8 = 0; nt8 < 8; ++nt8) {
        int nt = half * 8 + nt8;
        int kkl = nt8 * 16 + mm;
#pragma unroll
        for (int r = 0; r < 4; ++r) {
          int q = mt * 16 + quad * 4 + r;
          int ch = (kkl >> 3) ^ (q & 15);
          Pw[q * 128 + ch * 8 + (kkl & 7)] = f2bf(S[mt][nt][r]);
        }
      }
#pragma unroll
    for (int ksl = 0; ksl < 4; ++ksl) {
      bf16x8 pa[2];
#pragma unroll
      for (int mt = 0; mt < 2; ++mt) {
        int q = mt * 16 + mm;
        int ch = (ksl * 4 + quad) ^ (q & 15);
        pa[mt] = *(const bf16x8*)(Pw + q * 128 + ch * 8);
      }
#pragma unroll
      for (int dt = 0; dt < 4; ++dt) {
        int d = dt * 16 + mm;
        int ch = (ksl * 4 + quad) ^ (d & 15);
        bf16x8 vb = *(const bf16x8*)(Vp + d * 128 + ch * 8);
        O[0][dt] = mfma16(pa[0], vb, O[0][dt]);
        O[1][dt] = mfma16(pa[1], vb, O[1][dt]);
      }
    }
  }

  // epilogue: normalize and write X[b*4096+s][h*64+d] (bf16)
#pragma unroll
  for (int mt = 0; mt < 2; ++mt)
#pragma unroll
    for (int dt = 0; dt < 4; ++dt)
#pragma unroll
      for (int r = 0; r < 4; ++r) {
        int q = w * 32 + mt * 16 + quad * 4 + r;
        float val = O[mt][dt][r] / ls[mt][r];
        size_t row = (size_t)b * 4096 + n * 128 + q;
        X[row * 1024 + h * 64 + dt * 16 + mm] = f2bf(val);
      }
}

// ---------------- launch ----------------
extern "C" void kernel_launch(void* const* d_in, const int* in_sizes, int n_in,
                              void* d_out, int out_size, void* d_ws, size_t ws_size,
                              hipStream_t stream) {
  const float* inq   = (const float*)d_in[0];
  const float* wq    = (const float*)d_in[1];
  const float* bq    = (const float*)d_in[2];
  const float* wk    = (const float*)d_in[3];
  const float* bk    = (const float*)d_in[4];
  const float* wv    = (const float*)d_in[5];
  const float* bv    = (const float*)d_in[6];
  const float* wsort = (const float*)d_in[7];
  const float* bsort = (const float*)d_in[8];
  const float* wo    = (const float*)d_in[9];
  const float* bo    = (const float*)d_in[10];
  float* out = (float*)d_out;

  char* ws = (char*)d_ws;
  size_t off = 0;
  auto alloc = [&](size_t bytes) { char* p = ws + off; off += (bytes + 255) & ~(size_t)255; return p; };
  u16*  Qb    = (u16*)alloc(33554432);   // [4][16][4096][64] bf16, pre-scaled 1/8
  u16*  Kb    = (u16*)alloc(33554432);   // K [4][16][4096][64]
  u16*  Vbt   = (u16*)alloc(33554432);   // V transposed [4][16][64][4096]
  u16*  Ksort = (u16*)alloc(33554432);   // sorted K [4][16][32][128][64]
  u16*  Vsort = (u16*)alloc(33554432);   // sorted V^T [4][16][32][64][128]
  u16*  Abf   = (u16*)alloc(33554432);   // bf16 input; later aliased as X
  u16*  Wqkvt = (u16*)alloc(6291456);    // [3072][1024] bf16 (B^T)
  u16*  Wot   = (u16*)alloc(2097152);    // [1024][1024] bf16 (B^T)
  float* sumk = (float*)alloc(524288);   // [4][32][1024]
  float* so   = (float*)alloc(16384);    // [4][32][32]
  float* perm = (float*)alloc(16384);    // [4][32][32]
  u16*  X = Abf;   // alias: attention output over Abf (dead after k_gemm_qkv)

  k_cast<<<16384, 256, 0, stream>>>(inq, Abf);
  k_transpose4<<<dim3(32, 32, 4), dim3(32, 32), 0, stream>>>(wq, wk, wv, wo, Wqkvt, Wot);
  k_gemm_qkv<<<dim3(12, 64), 512, 0, stream>>>(Abf, Wqkvt, bq, bk, bv, Qb, Kb, Vbt, sumk);
  k_sortmm<<<dim3(32, 4), 256, 0, stream>>>(sumk, wsort, bsort, so);
  k_sinkhorn<<<4, 32, 0, stream>>>(so, perm);
  k_mix<<<dim3(32, 32, 4), 256, 0, stream>>>(Kb, Vbt, perm, Ksort, Vsort);
  k_attn<<<dim3(32, 16, 4), 256, 0, stream>>>(Qb, Kb, Ksort, Vbt, Vsort, X);
  k_gemm_out<<<dim3(4, 64), 512, 0, stream>>>(X, Wot, bo, out);
}

// Round 5
// 438.262 us; speedup vs baseline: 1.1628x; 1.0197x over previous
//
#include <hip/hip_runtime.h>
#include <stdint.h>

// ---------------- types / helpers ----------------
typedef short bf16x8 __attribute__((ext_vector_type(8)));
typedef float f32x4 __attribute__((ext_vector_type(4)));
typedef unsigned short u16;
typedef unsigned short u16x4 __attribute__((ext_vector_type(4)));

#define AS1 __attribute__((address_space(1)))
#define AS3 __attribute__((address_space(3)))

__device__ __forceinline__ void gll16(const void* g, void* l) {
  // async global->LDS, 16B per lane, LDS dest = wave-uniform base + lane*16
  __builtin_amdgcn_global_load_lds((const AS1 uint32_t*)g, (AS3 uint32_t*)l, 16, 0, 0);
}

__device__ __forceinline__ f32x4 mfma16(bf16x8 a, bf16x8 b, f32x4 c) {
  return __builtin_amdgcn_mfma_f32_16x16x32_bf16(a, b, c, 0, 0, 0);
}

__device__ __forceinline__ u16 f2bf(float f) {
  union { float f; uint32_t u; } c; c.f = f;
  uint32_t r = c.u + 0x7FFFu + ((c.u >> 16) & 1u);   // RNE
  return (u16)(r >> 16);
}
__device__ __forceinline__ float bf2f(u16 h) {
  union { uint32_t u; float f; } c; c.u = ((uint32_t)h) << 16; return c.f;
}

// ---------------- cast fp32 -> bf16 ----------------
__global__ __launch_bounds__(256) void k_cast(const float* __restrict__ in, u16* __restrict__ out) {
  int i = (blockIdx.x * 256 + threadIdx.x) * 4;
  float4 v = *(const float4*)(in + i);
  u16x4 r; r.x = f2bf(v.x); r.y = f2bf(v.y); r.z = f2bf(v.z); r.w = f2bf(v.w);
  *(u16x4*)(out + i) = r;
}

// ---------------- 4 weight transposes fp32 (1024x1024) -> bf16 transposed, one dispatch ----------------
__global__ __launch_bounds__(1024) void k_transpose4(
    const float* __restrict__ wq, const float* __restrict__ wk,
    const float* __restrict__ wv, const float* __restrict__ wo,
    u16* __restrict__ Wqkvt, u16* __restrict__ Wot) {
  __shared__ float t[32][33];
  const float* src; u16* dst;
  int z = blockIdx.z;
  if (z == 0)      { src = wq; dst = Wqkvt; }
  else if (z == 1) { src = wk; dst = Wqkvt + 1024 * 1024; }
  else if (z == 2) { src = wv; dst = Wqkvt + 2 * 1024 * 1024; }
  else             { src = wo; dst = Wot; }
  int tx = threadIdx.x, ty = threadIdx.y;
  t[ty][tx] = src[(size_t)(blockIdx.y * 32 + ty) * 1024 + blockIdx.x * 32 + tx];
  __syncthreads();
  dst[(size_t)(blockIdx.x * 32 + ty) * 1024 + blockIdx.y * 32 + tx] = f2bf(t[tx][ty]);
}

// ================= 256x256 / BK=64 / 8-wave pipelined main loop =================
// LDS 128 KiB: A dbuf [2][256][64] bf16 at 0, B dbuf [2][256][64] bf16 at 32768 (u16 units).
// Chunk swizzle within a 64-col row: phys = logical ^ (row&7). Staging unit = 64 rows = 8KB
// = one gll16 per 512-thread block. Per K-tile: A units 0..3, B units 0..3.
//
// Register-resident tile schedule (3 barriers, 24 ds_reads, 1.5 exposed lgkm per tile):
//  ph0: af<-A{0,2}(C)[8rd], bfA<-B.h0(C)[4rd]; STB(0,1,t+1)->!C; lgkm0;
//       hoist bfB<-B.h1(C)[4rd] (completes under MFMA); MFMA(0,0)[af,bfA];  B1
//  ph1: STB(2,3,t+1)->!C, STA(0,2,t+2)->C; lgkm0(free); MFMA(0,1)[af,bfB]
//  ph2: af<-A{1,3}(C)[8rd]; lgkm0(part-hidden); MFMA(1,1)[af,bfB];          B2
//  ph3: STA(1,3,t+2)->C; MFMA(1,0)[af,bfA]; vmcnt(4); B3
// Hazard audit: A{0,2}(C) read ph0 < B1 < restage ph1. A{1,3}(C) read ph2 < B2 < restage
// ph3. B(!C) units all read in tile t-1 ph0 < B3(t-1) < restage tile t. vmcnt ledger
// identical to the verified round-4 schedule (8 issues/tile, 4 left in flight).
__device__ __forceinline__ void gemm256_loop(
    const u16* __restrict__ Ag, const u16* __restrict__ Bg,
    u16* lds, int m0, int n0, f32x4 (&acc)[8][4])
{
  const int tid = threadIdx.x, lane = tid & 63, w = tid >> 6;
  const int wm = w >> 2, wn = w & 3;
  const int l8 = lane >> 3, c7 = lane & 7;
  const int mm = lane & 15, quad = lane >> 4;
  const int ch0 = (quad ^ (mm & 7)) * 8;          // phys chunk for ks=0 (u16 offset)
  const int ch1 = ((quad ^ (mm & 7)) ^ 4) * 8;    // phys chunk for ks=1

  const u16* aSt = Ag + (size_t)(m0 + w * 8 + l8) * 1024 + (c7 ^ l8) * 8;
  const u16* bSt = Bg + (size_t)(n0 + w * 8 + l8) * 1024 + (c7 ^ l8) * 8;
  u16* ldsAw = lds + w * 512;
  u16* ldsBw = lds + 32768 + w * 512;
  const u16* aR0 = lds + (wm * 128 + mm) * 64 + ch0;
  const u16* aR1 = lds + (wm * 128 + mm) * 64 + ch1;
  const u16* bR0 = lds + 32768 + (wn * 64 + mm) * 64 + ch0;
  const u16* bR1 = lds + 32768 + (wn * 64 + mm) * 64 + ch1;

#define STA(q, kt, buf) gll16(aSt + (q) * 65536 + (kt) * 64, ldsAw + (buf) * 16384 + (q) * 4096)
#define STB(q, kt, buf) gll16(bSt + (q) * 65536 + (kt) * 64, ldsBw + (buf) * 16384 + (q) * 4096)

#define LDA(C, MH) do {                                                                  \
    _Pragma("unroll")                                                                    \
    for (int i = 0; i < 4; ++i) {                                                        \
      af[i][0] = *(const bf16x8*)(aR0 + (C) * 16384 + ((MH) * 64 + i * 16) * 64);        \
      af[i][1] = *(const bf16x8*)(aR1 + (C) * 16384 + ((MH) * 64 + i * 16) * 64);        \
    }                                                                                    \
  } while (0)
#define LDBv(C, NH, DST) do {                                                            \
    _Pragma("unroll")                                                                    \
    for (int j = 0; j < 2; ++j) {                                                        \
      DST[j][0] = *(const bf16x8*)(bR0 + (C) * 16384 + ((NH) * 32 + j * 16) * 64);       \
      DST[j][1] = *(const bf16x8*)(bR1 + (C) * 16384 + ((NH) * 32 + j * 16) * 64);       \
    }                                                                                    \
  } while (0)
#define MM(MH, NH, BF) do {                                                              \
    __builtin_amdgcn_s_setprio(1);                                                       \
    _Pragma("unroll")                                                                    \
    for (int ks = 0; ks < 2; ++ks)                                                       \
      _Pragma("unroll")                                                                  \
      for (int i = 0; i < 4; ++i)                                                        \
        _Pragma("unroll")                                                                \
        for (int j = 0; j < 2; ++j)                                                      \
          acc[(MH) * 4 + i][(NH) * 2 + j] =                                              \
              mfma16(af[i][ks], BF[j][ks], acc[(MH) * 4 + i][(NH) * 2 + j]);             \
    __builtin_amdgcn_s_setprio(0);                                                       \
  } while (0)
#define LGKM0 do {                                                                       \
    asm volatile("s_waitcnt lgkmcnt(0)" ::: "memory");                                   \
    __builtin_amdgcn_sched_barrier(0);                                                   \
  } while (0)

// one K-tile: TT = tile index (runtime), C = LDS buffer (compile-time 0/1)
#define TILE(TT, C) do {                                                                 \
    const int t1 = (TT) + 1, t2 = (TT) + 2;                                              \
    const bool sB = t1 < 16, sA = t2 < 16;                                               \
    /* ph0 */                                                                            \
    LDA(C, 0); LDBv(C, 0, bfA);                                                          \
    if (sB) { STB(0, t1, 1 - (C)); STB(1, t1, 1 - (C)); }                                \
    LGKM0;                                                                               \
    LDBv(C, 1, bfB);                                                                     \
    __builtin_amdgcn_sched_barrier(0);                                                   \
    MM(0, 0, bfA);                                                                       \
    __builtin_amdgcn_s_barrier();                              /* B1 */                  \
    /* ph1 */                                                                            \
    if (sB) { STB(2, t1, 1 - (C)); STB(3, t1, 1 - (C)); }                                \
    if (sA) { STA(0, t2, C); STA(2, t2, C); }                                            \
    LGKM0;                                                                               \
    MM(0, 1, bfB);                                                                       \
    /* ph2 (no barrier) */                                                               \
    LDA(C, 1);                                                                           \
    LGKM0;                                                                               \
    MM(1, 1, bfB);                                                                       \
    __builtin_amdgcn_s_barrier();                              /* B2 */                  \
    /* ph3 */                                                                            \
    if (sA) { STA(1, t2, C); STA(3, t2, C); }                                            \
    MM(1, 0, bfA);                                                                       \
    if ((TT) < 14)       asm volatile("s_waitcnt vmcnt(4)" ::: "memory");                \
    else if ((TT) == 14) asm volatile("s_waitcnt vmcnt(0)" ::: "memory");                \
    __builtin_amdgcn_s_barrier();                              /* B3 */                  \
  } while (0)

#pragma unroll
  for (int i = 0; i < 8; ++i)
#pragma unroll
    for (int j = 0; j < 4; ++j) acc[i][j] = (f32x4){0.f, 0.f, 0.f, 0.f};

  // prologue: A,B of tile 0 -> buf0; all of A of tile 1 -> buf1 (stays in flight)
  STA(0, 0, 0); STA(1, 0, 0); STA(2, 0, 0); STA(3, 0, 0);
  STB(0, 0, 0); STB(1, 0, 0); STB(2, 0, 0); STB(3, 0, 0);
  STA(0, 1, 1); STA(1, 1, 1); STA(2, 1, 1); STA(3, 1, 1);
  asm volatile("s_waitcnt vmcnt(4)" ::: "memory");
  __builtin_amdgcn_s_barrier();

#pragma unroll 1
  for (int t = 0; t < 16; t += 2) {
    bf16x8 af[4][2]; bf16x8 bfA[2][2]; bf16x8 bfB[2][2];
    TILE(t, 0);
    TILE(t + 1, 1);
  }
#undef TILE
#undef LGKM0
#undef MM
#undef LDA
#undef LDBv
#undef STA
#undef STB
}

// ---------------- fused QKV GEMM: A[16384x1024] * Wqkvt[3072x1024]^T ----------------
// 256x256 tile, 512 threads, 128 KiB LDS, 1 block/CU. XCD-chunked block swizzle (768=8*96).
__global__ __launch_bounds__(512, 2) void k_gemm_qkv(
    const u16* __restrict__ A, const u16* __restrict__ Bt,
    const float* __restrict__ bq, const float* __restrict__ bk, const float* __restrict__ bv,
    u16* __restrict__ Qb, u16* __restrict__ Kb, u16* __restrict__ Vbt, float* __restrict__ sumk)
{
  __shared__ __align__(16) u16 LDS[65536];   // 128 KiB
  int lin = blockIdx.x + 12 * blockIdx.y;          // 0..767
  int nb = (lin & 7) * 96 + (lin >> 3);            // bijective XCD chunking
  const int m0 = (nb / 12) * 256, n0 = (nb % 12) * 256;
  f32x4 acc[8][4];
  gemm256_loop(A, Bt, LDS, m0, n0, acc);

  const int tid = threadIdx.x, lane = tid & 63, w = tid >> 6;
  const int wm = w >> 2, wn = w & 3;
  const int mm = lane & 15, quad = lane >> 4;
  const int sel = n0 >> 10;                   // 0=Q, 1=K, 2=V (uniform per block)
  const float* bias = sel == 0 ? bq : (sel == 1 ? bk : bv);
  // NOTE: all waves are past the loop's final barrier -> LDS free; each wave uses only
  // its own 16KB region below (no cross-wave traffic, no further barriers needed).
  u16* W = LDS + w * 8192;

  if (sel == 2) {
    // ---- V epilogue: per-wave LDS transpose, then coalesced d-major 8B stores ----
#pragma unroll
    for (int nf = 0; nf < 4; ++nf) {
      int d = nf * 16 + mm;
      float bval = bias[((n0 & 1023) + wn * 64 + nf * 16 + mm)];
#pragma unroll
      for (int mf = 0; mf < 8; ++mf) {
        int c = mf * 4 + quad;
        u16x4 pk;
        pk.x = f2bf(acc[mf][nf][0] + bval);
        pk.y = f2bf(acc[mf][nf][1] + bval);
        pk.z = f2bf(acc[mf][nf][2] + bval);
        pk.w = f2bf(acc[mf][nf][3] + bval);
        *(u16x4*)(W + d * 128 + (c ^ (d & 15)) * 4) = pk;
      }
    }
    asm volatile("s_waitcnt lgkmcnt(0)" ::: "memory");
    int h_w = ((n0 & 1023) >> 6) + wn;
    int b_ = m0 >> 12;
    int c = lane & 31, dpar = lane >> 5;
    size_t gbase = ((size_t)(b_ * 16 + h_w) * 64) * 4096 + (m0 & 4095) + wm * 128 + c * 4;
#pragma unroll
    for (int dd = 0; dd < 32; ++dd) {
      int d = dd * 2 + dpar;
      u16x4 v = *(const u16x4*)(W + d * 128 + (c ^ (d & 15)) * 4);
      *(u16x4*)(Vbt + gbase + (size_t)d * 4096) = v;
    }
    return;
  }

  // ---- Q/K epilogue: per-wave LDS re-tile [128s][64d], then 16B/lane linear stores ----
  const float scl = sel == 0 ? 0.125f : 1.0f;
#pragma unroll
  for (int nf = 0; nf < 4; ++nf) {
    float bval = bias[(n0 & 1023) + wn * 64 + nf * 16 + mm];
#pragma unroll
    for (int mf = 0; mf < 8; ++mf)
#pragma unroll
      for (int r = 0; r < 4; ++r)
        W[(mf * 16 + quad * 4 + r) * 64 + nf * 16 + mm] = f2bf((acc[mf][nf][r] + bval) * scl);
  }
  asm volatile("s_waitcnt lgkmcnt(0)" ::: "memory");
  {
    int h = ((n0 & 1023) >> 6) + wn;
    int mg0 = m0 + wm * 128;
    int b_ = mg0 >> 12;
    u16* dst = (sel == 0 ? Qb : Kb) + ((size_t)(b_ * 16 + h) * 4096 + (mg0 & 4095)) * 64;
    int l8 = lane >> 3, c8 = lane & 7;
#pragma unroll
    for (int i = 0; i < 16; ++i) {
      int s = i * 8 + l8;
      *(bf16x8*)(dst + s * 64 + c8 * 8) = *(const bf16x8*)(W + s * 64 + c8 * 8);
    }
  }

  if (sel == 1) {
    // per-wave: wave (wm,wn) covers rows [m0+wm*128, +128) x cols [wn*64, +64)
    // -> exactly one sumk block (nb = m0/128 + wm) per wave, no cross-wave reduction.
#pragma unroll
    for (int nf = 0; nf < 4; ++nf) {
      float ssum = 0.f;
#pragma unroll
      for (int mf = 0; mf < 8; ++mf)
#pragma unroll
        for (int r = 0; r < 4; ++r) ssum += acc[mf][nf][r];
      ssum += __shfl_xor(ssum, 16);
      ssum += __shfl_xor(ssum, 32);            // sum over the 4 quads -> 128 rows
      if (quad == 0) {
        int colg = (n0 - 1024) + wn * 64 + nf * 16 + mm;
        int b_ = m0 >> 12, nb2 = ((m0 >> 7) & 31) + wm;
        sumk[(size_t)(b_ * 32 + nb2) * 1024 + colg] = ssum + 128.f * bias[colg];
      }
    }
  }
}

// ---------------- output GEMM: X[16384x1024] * Wot[1024x1024]^T + bo -> fp32 ----------------
__global__ __launch_bounds__(512, 2) void k_gemm_out(
    const u16* __restrict__ A, const u16* __restrict__ Bt,
    const float* __restrict__ bo, float* __restrict__ out)
{
  __shared__ __align__(16) u16 LDS[65536];   // 128 KiB
  int lin = blockIdx.x + 4 * blockIdx.y;           // 0..255
  int nb = (lin & 7) * 32 + (lin >> 3);            // bijective XCD chunking
  const int m0 = (nb / 4) * 256, n0 = (nb % 4) * 256;
  f32x4 acc[8][4];
  gemm256_loop(A, Bt, LDS, m0, n0, acc);

  const int tid = threadIdx.x, lane = tid & 63, w = tid >> 6;
  const int wm = w >> 2, wn = w & 3;
  const int mm = lane & 15, quad = lane >> 4;
#pragma unroll
  for (int nf = 0; nf < 4; ++nf) {
    int ng = n0 + wn * 64 + nf * 16 + mm;
    float bval = bo[ng];
#pragma unroll
    for (int mf = 0; mf < 8; ++mf)
#pragma unroll
      for (int r = 0; r < 4; ++r) {
        int mg = m0 + wm * 128 + mf * 16 + quad * 4 + r;
        out[(size_t)mg * 1024 + ng] = acc[mf][nf][r] + bval;
      }
  }
}

// ---------------- sort logits: sumk[b][n][1024] @ w_sort[1024][32] + b_sort ----------------
__global__ __launch_bounds__(256) void k_sortmm(const float* __restrict__ sumk, const float* __restrict__ wsort,
                                                const float* __restrict__ bsort, float* __restrict__ so) {
  __shared__ float red[256];
  int n = blockIdx.x, b = blockIdx.y, t = threadIdx.x;
  int m = t & 31, kp = t >> 5;
  const float* row = sumk + (size_t)(b * 32 + n) * 1024;
  float acc = 0.f;
  for (int c = kp * 128; c < kp * 128 + 128; ++c) acc += row[c] * wsort[c * 32 + m];
  red[t] = acc;
  __syncthreads();
  if (t < 32) {
    float s = bsort[t];
#pragma unroll
    for (int q = 0; q < 8; ++q) s += red[q * 32 + t];
    so[(size_t)(b * 32 + n) * 32 + t] = s;
  }
}

// ---------------- Sinkhorn (5 iters) + clip + exp ----------------
__global__ __launch_bounds__(32) void k_sinkhorn(const float* __restrict__ so, float* __restrict__ perm) {
  __shared__ float A[32][33];
  int b = blockIdx.x, t = threadIdx.x;
  for (int i = 0; i < 32; ++i) A[i][t] = so[(size_t)(b * 32 + i) * 32 + t];
  __syncthreads();
  for (int it = 0; it < 5; ++it) {
    { // row LSE (axis=2)
      float mx = -1e30f;
      for (int j = 0; j < 32; ++j) mx = fmaxf(mx, A[t][j]);
      float s = 0.f;
      for (int j = 0; j < 32; ++j) s += __expf(A[t][j] - mx);
      float l = mx + __logf(s);
      for (int j = 0; j < 32; ++j) A[t][j] -= l;
    }
    __syncthreads();
    { // col LSE (axis=1)
      float mx = -1e30f;
      for (int j = 0; j < 32; ++j) mx = fmaxf(mx, A[j][t]);
      float s = 0.f;
      for (int j = 0; j < 32; ++j) s += __expf(A[j][t] - mx);
      float l = mx + __logf(s);
      for (int j = 0; j < 32; ++j) A[j][t] -= l;
    }
    __syncthreads();
  }
  for (int i = 0; i < 32; ++i)
    perm[(size_t)(b * 32 + i) * 32 + t] = __expf(fminf(fmaxf(A[i][t], -1.f), 1.f));
}

// ---------------- merged block mix: y<16 -> K-mix (h=y), y>=16 -> V-mix (h=y-16) ----------------
__global__ __launch_bounds__(256) void k_mix(
    const u16* __restrict__ Kb, const u16* __restrict__ Vbt, const float* __restrict__ perm,
    u16* __restrict__ Ksort, u16* __restrict__ Vsort)
{
  __shared__ float P[32][32];
  int b = blockIdx.z, y = blockIdx.y, xg = blockIdx.x;
  int tid = threadIdx.x;
#pragma unroll
  for (int i = 0; i < 4; ++i) {
    int idx = i * 256 + tid;
    P[idx >> 5][idx & 31] = perm[b * 1024 + idx];
  }
  __syncthreads();
  if (y < 16) {
    // K mix: Ksort[b][h][n][128s][64d] = sum_m perm[n][m] * K[b][h][m*128+s][d]
    int h = y;
    int ss = xg * 4 + (tid >> 6), d = tid & 63;
    const u16* Kg = Kb + (size_t)(b * 16 + h) * 262144;
    float xk[32];
#pragma unroll
    for (int m = 0; m < 32; ++m) xk[m] = bf2f(Kg[(size_t)(m * 128 + ss) * 64 + d]);
    size_t tbase = (size_t)((b * 16 + h) * 32) * 8192;
#pragma unroll
    for (int nn = 0; nn < 32; ++nn) {
      float sk = 0.f;
#pragma unroll
      for (int m4 = 0; m4 < 8; ++m4) {
        float4 pv = *(const float4*)&P[nn][m4 * 4];
        sk += pv.x * xk[m4 * 4 + 0] + pv.y * xk[m4 * 4 + 1] + pv.z * xk[m4 * 4 + 2] + pv.w * xk[m4 * 4 + 3];
      }
      Ksort[tbase + (size_t)nn * 8192 + ss * 64 + d] = f2bf(sk);
    }
  } else {
    // V mix (transposed): Vsort[b][h][n][64d][128s] from Vbt[b][h][d][s]
    int h = y - 16;
    int d = xg * 2 + (tid >> 7), ss = tid & 127;
    const u16* Vg = Vbt + ((size_t)(b * 16 + h) * 64 + d) * 4096;
    float xv[32];
#pragma unroll
    for (int m = 0; m < 32; ++m) xv[m] = bf2f(Vg[m * 128 + ss]);
    size_t tbase = (size_t)((b * 16 + h) * 32) * 8192;
#pragma unroll
    for (int nn = 0; nn < 32; ++nn) {
      float sv = 0.f;
#pragma unroll
      for (int m4 = 0; m4 < 8; ++m4) {
        float4 pv = *(const float4*)&P[nn][m4 * 4];
        sv += pv.x * xv[m4 * 4 + 0] + pv.y * xv[m4 * 4 + 1] + pv.z * xv[m4 * 4 + 2] + pv.w * xv[m4 * 4 + 3];
      }
      Vsort[tbase + (size_t)nn * 8192 + d * 128 + ss] = f2bf(sv);
    }
  }
}

// ---------------- attention per (b,n,h): softmax(Q Kcat^T) Vcat ----------------
__global__ __launch_bounds__(256, 2) void k_attn(
    const u16* __restrict__ Qb, const u16* __restrict__ Kb, const u16* __restrict__ Ksort,
    const u16* __restrict__ Vbt, const u16* __restrict__ Vsort, u16* __restrict__ X)
{
  __shared__ u16 Ks[16384];    // 256 kk x 64 d (swizzled); later overlaid by per-wave P
  __shared__ u16 Vlo[8192];    // 64 d x 128 kk (orig half, swizzled)
  __shared__ u16 Vhi[8192];    // 64 d x 128 kk (sorted half, swizzled)
  int tid = threadIdx.x, lane = tid & 63, w = tid >> 6;
  int n = blockIdx.x, h = blockIdx.y, b = blockIdx.z;
  size_t bh = (size_t)(b * 16 + h);
  size_t tileK = bh * 32 + n;

  { // stage Kcat rows: [0,128) from Kb, [128,256) from Ksort. chunk = 8 rows x 64 u16.
    int l8 = lane >> 3, sl8 = lane & 7;
    const u16* Korig = Kb + (bh * 4096 + (size_t)n * 128) * 64;
    const u16* Ksrt  = Ksort + tileK * 8192;
#pragma unroll
    for (int c = 0; c < 8; ++c) {
      int cc = w * 8 + c;
      int r = cc * 8 + l8;
      int pk = sl8 ^ (r & 7);
      const u16* src = (cc < 16) ? (Korig + (size_t)r * 64 + pk * 8)
                                 : (Ksrt + (size_t)(r - 128) * 64 + pk * 8);
      gll16(src, Ks + cc * 512);
    }
    // stage V panels: chunk = 4 d-rows x 128 u16.
    int l16 = lane >> 4, sl16 = lane & 15;
    const u16* Vorig = Vbt + bh * 262144 + (size_t)n * 128;
    const u16* Vsrt  = Vsort + tileK * 8192;
#pragma unroll
    for (int c = 0; c < 4; ++c) {
      int cc = w * 4 + c;
      int d = cc * 4 + l16;
      int pv = sl16 ^ (d & 15);
      gll16(Vorig + (size_t)d * 4096 + pv * 8, Vlo + cc * 512);
      gll16(Vsrt + (size_t)d * 128 + pv * 8, Vhi + cc * 512);
    }
  }

  int mm = lane & 15, quad = lane >> 4;
  bf16x8 qf[2][2];
  {
    size_t qrow = bh * 4096 + n * 128 + w * 32;
#pragma unroll
    for (int mt = 0; mt < 2; ++mt)
#pragma unroll
      for (int ks = 0; ks < 2; ++ks)
        qf[mt][ks] = *(const bf16x8*)(Qb + (qrow + mt * 16 + mm) * 64 + ks * 32 + quad * 8);
  }
  __syncthreads();

  // S = Qs @ Kcat^T  (wave w owns q rows [w*32, w*32+32))
  f32x4 S[2][16];
#pragma unroll
  for (int mt = 0; mt < 2; ++mt)
#pragma unroll
    for (int nt = 0; nt < 16; ++nt) S[mt][nt] = (f32x4){0.f, 0.f, 0.f, 0.f};
#pragma unroll
  for (int nt = 0; nt < 16; ++nt) {
    int kk = nt * 16 + mm;
#pragma unroll
    for (int ks = 0; ks < 2; ++ks) {
      int ch = (ks * 4 + quad) ^ (kk & 7);
      bf16x8 bk = *(const bf16x8*)(Ks + kk * 64 + ch * 8);
      S[0][nt] = mfma16(qf[0][ks], bk, S[0][nt]);
      S[1][nt] = mfma16(qf[1][ks], bk, S[1][nt]);
    }
  }

  // softmax over kk (C-layout: row = quad*4+r, col = mm across nt)
  float mx[2][4], ls[2][4];
#pragma unroll
  for (int mt = 0; mt < 2; ++mt)
#pragma unroll
    for (int r = 0; r < 4; ++r) {
      float v = S[mt][0][r];
#pragma unroll
      for (int nt = 1; nt < 16; ++nt) v = fmaxf(v, S[mt][nt][r]);
#pragma unroll
      for (int o = 1; o < 16; o <<= 1) v = fmaxf(v, __shfl_xor(v, o));
      mx[mt][r] = v;
    }
#pragma unroll
  for (int mt = 0; mt < 2; ++mt)
#pragma unroll
    for (int nt = 0; nt < 16; ++nt)
#pragma unroll
      for (int r = 0; r < 4; ++r)
        S[mt][nt][r] = __expf(S[mt][nt][r] - mx[mt][r]);
#pragma unroll
  for (int mt = 0; mt < 2; ++mt)
#pragma unroll
    for (int r = 0; r < 4; ++r) {
      float s = 0.f;
#pragma unroll
      for (int nt = 0; nt < 16; ++nt) s += S[mt][nt][r];
#pragma unroll
      for (int o = 1; o < 16; o <<= 1) s += __shfl_xor(s, o);
      ls[mt][r] = s;
    }

  __syncthreads();   // all waves done reading Ks before overlaying with P

  // PV in two kk halves; P (bf16) round-trips through per-wave LDS region over Ks
  u16* Pw = Ks + w * 4096;   // 32 q-rows x 128 kk per half (8KB per wave)
  f32x4 O[2][4];
#pragma unroll
  for (int mt = 0; mt < 2; ++mt)
#pragma unroll
    for (int dt = 0; dt < 4; ++dt) O[mt][dt] = (f32x4){0.f, 0.f, 0.f, 0.f};

#pragma unroll
  for (int half = 0; half < 2; ++half) {
    const u16* Vp = half == 0 ? Vlo : Vhi;
#pragma unroll
    for (int mt = 0; mt < 2; ++mt)
#pragma unroll
      for (int nt8 = 0; nt8 < 8; ++nt8) {
        int nt = half * 8 + nt8;
        int kkl = nt8 * 16 + mm;
#pragma unroll
        for (int r = 0; r < 4; ++r) {
          int q = mt * 16 + quad * 4 + r;
          int ch = (kkl >> 3) ^ (q & 15);
          Pw[q * 128 + ch * 8 + (kkl & 7)] = f2bf(S[mt][nt][r]);
        }
      }
#pragma unroll
    for (int ksl = 0; ksl < 4; ++ksl) {
      bf16x8 pa[2];
#pragma unroll
      for (int mt = 0; mt < 2; ++mt) {
        int q = mt * 16 + mm;
        int ch = (ksl * 4 + quad) ^ (q & 15);
        pa[mt] = *(const bf16x8*)(Pw + q * 128 + ch * 8);
      }
#pragma unroll
      for (int dt = 0; dt < 4; ++dt) {
        int d = dt * 16 + mm;
        int ch = (ksl * 4 + quad) ^ (d & 15);
        bf16x8 vb = *(const bf16x8*)(Vp + d * 128 + ch * 8);
        O[0][dt] = mfma16(pa[0], vb, O[0][dt]);
        O[1][dt] = mfma16(pa[1], vb, O[1][dt]);
      }
    }
  }

  // epilogue: normalize and write X[b*4096+s][h*64+d] (bf16)
#pragma unroll
  for (int mt = 0; mt < 2; ++mt)
#pragma unroll
    for (int dt = 0; dt < 4; ++dt)
#pragma unroll
      for (int r = 0; r < 4; ++r) {
        int q = w * 32 + mt * 16 + quad * 4 + r;
        float val = O[mt][dt][r] / ls[mt][r];
        size_t row = (size_t)b * 4096 + n * 128 + q;
        X[row * 1024 + h * 64 + dt * 16 + mm] = f2bf(val);
      }
}

// ---------------- launch ----------------
extern "C" void kernel_launch(void* const* d_in, const int* in_sizes, int n_in,
                              void* d_out, int out_size, void* d_ws, size_t ws_size,
                              hipStream_t stream) {
  const float* inq   = (const float*)d_in[0];
  const float* wq    = (const float*)d_in[1];
  const float* bq    = (const float*)d_in[2];
  const float* wk    = (const float*)d_in[3];
  const float* bk    = (const float*)d_in[4];
  const float* wv    = (const float*)d_in[5];
  const float* bv    = (const float*)d_in[6];
  const float* wsort = (const float*)d_in[7];
  const float* bsort = (const float*)d_in[8];
  const float* wo    = (const float*)d_in[9];
  const float* bo    = (const float*)d_in[10];
  float* out = (float*)d_out;

  char* ws = (char*)d_ws;
  size_t off = 0;
  auto alloc = [&](size_t bytes) { char* p = ws + off; off += (bytes + 255) & ~(size_t)255; return p; };
  u16*  Qb    = (u16*)alloc(33554432);   // [4][16][4096][64] bf16, pre-scaled 1/8
  u16*  Kb    = (u16*)alloc(33554432);   // K [4][16][4096][64]
  u16*  Vbt   = (u16*)alloc(33554432);   // V transposed [4][16][64][4096]
  u16*  Ksort = (u16*)alloc(33554432);   // sorted K [4][16][32][128][64]
  u16*  Vsort = (u16*)alloc(33554432);   // sorted V^T [4][16][32][64][128]
  u16*  Abf   = (u16*)alloc(33554432);   // bf16 input; later aliased as X
  u16*  Wqkvt = (u16*)alloc(6291456);    // [3072][1024] bf16 (B^T)
  u16*  Wot   = (u16*)alloc(2097152);    // [1024][1024] bf16 (B^T)
  float* sumk = (float*)alloc(524288);   // [4][32][1024]
  float* so   = (float*)alloc(16384);    // [4][32][32]
  float* perm = (float*)alloc(16384);    // [4][32][32]
  u16*  X = Abf;   // alias: attention output over Abf (dead after k_gemm_qkv)

  k_cast<<<16384, 256, 0, stream>>>(inq, Abf);
  k_transpose4<<<dim3(32, 32, 4), dim3(32, 32), 0, stream>>>(wq, wk, wv, wo, Wqkvt, Wot);
  k_gemm_qkv<<<dim3(12, 64), 512, 0, stream>>>(Abf, Wqkvt, bq, bk, bv, Qb, Kb, Vbt, sumk);
  k_sortmm<<<dim3(32, 4), 256, 0, stream>>>(sumk, wsort, bsort, so);
  k_sinkhorn<<<4, 32, 0, stream>>>(so, perm);
  k_mix<<<dim3(32, 32, 4), 256, 0, stream>>>(Kb, Vbt, perm, Ksort, Vsort);
  k_attn<<<dim3(32, 16, 4), 256, 0, stream>>>(Qb, Kb, Ksort, Vbt, Vsort, X);
  k_gemm_out<<<dim3(4, 64), 512, 0, stream>>>(X, Wot, bo, out);
}

// Round 8
// 428.807 us; speedup vs baseline: 1.1885x; 1.0221x over previous
//
#include <hip/hip_runtime.h>
#include <stdint.h>

// ---------------- types / helpers ----------------
typedef short bf16x8 __attribute__((ext_vector_type(8)));
typedef float f32x4 __attribute__((ext_vector_type(4)));
typedef unsigned short u16;
typedef unsigned short u16x4 __attribute__((ext_vector_type(4)));

#define AS1 __attribute__((address_space(1)))
#define AS3 __attribute__((address_space(3)))

__device__ __forceinline__ void gll16(const void* g, void* l) {
  // async global->LDS, 16B per lane, LDS dest = wave-uniform base + lane*16
  __builtin_amdgcn_global_load_lds((const AS1 uint32_t*)g, (AS3 uint32_t*)l, 16, 0, 0);
}

__device__ __forceinline__ f32x4 mfma16(bf16x8 a, bf16x8 b, f32x4 c) {
  return __builtin_amdgcn_mfma_f32_16x16x32_bf16(a, b, c, 0, 0, 0);
}

__device__ __forceinline__ u16 f2bf(float f) {
  union { float f; uint32_t u; } c; c.f = f;
  uint32_t r = c.u + 0x7FFFu + ((c.u >> 16) & 1u);   // RNE
  return (u16)(r >> 16);
}
__device__ __forceinline__ float bf2f(u16 h) {
  union { uint32_t u; float f; } c; c.u = ((uint32_t)h) << 16; return c.f;
}

// ---------------- cast fp32 -> bf16 ----------------
__global__ __launch_bounds__(256) void k_cast(const float* __restrict__ in, u16* __restrict__ out) {
  int i = (blockIdx.x * 256 + threadIdx.x) * 4;
  float4 v = *(const float4*)(in + i);
  u16x4 r; r.x = f2bf(v.x); r.y = f2bf(v.y); r.z = f2bf(v.z); r.w = f2bf(v.w);
  *(u16x4*)(out + i) = r;
}

// ---------------- 4 weight transposes fp32 (1024x1024) -> bf16 transposed, one dispatch ----------------
__global__ __launch_bounds__(1024) void k_transpose4(
    const float* __restrict__ wq, const float* __restrict__ wk,
    const float* __restrict__ wv, const float* __restrict__ wo,
    u16* __restrict__ Wqkvt, u16* __restrict__ Wot) {
  __shared__ float t[32][33];
  const float* src; u16* dst;
  int z = blockIdx.z;
  if (z == 0)      { src = wq; dst = Wqkvt; }
  else if (z == 1) { src = wk; dst = Wqkvt + 1024 * 1024; }
  else if (z == 2) { src = wv; dst = Wqkvt + 2 * 1024 * 1024; }
  else             { src = wo; dst = Wot; }
  int tx = threadIdx.x, ty = threadIdx.y;
  t[ty][tx] = src[(size_t)(blockIdx.y * 32 + ty) * 1024 + blockIdx.x * 32 + tx];
  __syncthreads();
  dst[(size_t)(blockIdx.x * 32 + ty) * 1024 + blockIdx.y * 32 + tx] = f2bf(t[tx][ty]);
}

// ================= 256x256 / BK=64 / 8-wave pipelined main loop =================
// LDS 128 KiB: A dbuf [2][256][64] bf16 at 0, B dbuf [2][256][64] bf16 at 32768 (u16 units).
// Chunk swizzle within a 64-col row: phys = logical ^ (row&7). Staging unit = 64 rows = 8KB
// = one gll16 per 512-thread block. Per K-tile: A units 0..3, B units 0..3.
//
// 2-barrier tile schedule (counted lgkm in ph0; af reloaded ONLY in ph2 — the round-5
// variant that issued LDA(C,1) in ph1 clobbered af while MM(0,1) still needed MH0 data):
//  ph0: rd af(MH0)[8]+bfA[4] | fence | rd bfB[4] | STB(0,1,t+1)->!C; lgkmcnt(4); MM(0,0)
//  ph1: STB(2,3,t+1)->!C; lgkmcnt(0) [bfB — hidden under MM(0,0)]; MM(0,1)
//  ph2: rd af(MH1)[8]; lgkmcnt(0) [exposed ~200cy]; MM(1,1)
//       B2   (separates ALL reads of buf C from ph3's restage)
//  ph3: STA(0..3,t+2)->C; MM(1,0) [registers only]; vmcnt(4); B3
// Register lifetimes: af MH0 live ph0-ph1 (MM(0,0),MM(0,1)); af MH1 live ph2-ph3;
// bfA live ph0-ph3 (MM(0,0),MM(1,0)); bfB live ph0-ph2 (MM(0,1),MM(1,1)). No clobber.
// LDS hazards: every wave's buf-C ds_reads retire before B2 (ph1/ph2 lgkmcnt(0)); STA->C
// after B2. STB->!C vs !C's reads: separated by tile t-1's B2+B3.
// vmcnt ledger (per wave): tile start: STA(t+1)x4; ph0 +2, ph1 +2, ph3 +4 = 12;
// vmcnt(4) retires the 8 oldest = ALL of tile t+1 (A+B), leaves STA(t+2)x4.
// t=14: vmcnt(0) drains; t=15 issues nothing. Flight: STB >= 2.5 ph, STA >= 5 ph.
__device__ __forceinline__ void gemm256_loop(
    const u16* __restrict__ Ag, const u16* __restrict__ Bg,
    u16* lds, int m0, int n0, f32x4 (&acc)[8][4])
{
  const int tid = threadIdx.x, lane = tid & 63, w = tid >> 6;
  const int wm = w >> 2, wn = w & 3;
  const int l8 = lane >> 3, c7 = lane & 7;
  const int mm = lane & 15, quad = lane >> 4;
  const int ch0 = (quad ^ (mm & 7)) * 8;          // phys chunk for ks=0 (u16 offset)
  const int ch1 = ((quad ^ (mm & 7)) ^ 4) * 8;    // phys chunk for ks=1

  const u16* aSt = Ag + (size_t)(m0 + w * 8 + l8) * 1024 + (c7 ^ l8) * 8;
  const u16* bSt = Bg + (size_t)(n0 + w * 8 + l8) * 1024 + (c7 ^ l8) * 8;
  u16* ldsAw = lds + w * 512;
  u16* ldsBw = lds + 32768 + w * 512;
  const u16* aR0 = lds + (wm * 128 + mm) * 64 + ch0;
  const u16* aR1 = lds + (wm * 128 + mm) * 64 + ch1;
  const u16* bR0 = lds + 32768 + (wn * 64 + mm) * 64 + ch0;
  const u16* bR1 = lds + 32768 + (wn * 64 + mm) * 64 + ch1;

#define STA(q, kt, buf) gll16(aSt + (q) * 65536 + (kt) * 64, ldsAw + (buf) * 16384 + (q) * 4096)
#define STB(q, kt, buf) gll16(bSt + (q) * 65536 + (kt) * 64, ldsBw + (buf) * 16384 + (q) * 4096)

#define LDA(C, MH) do {                                                                  \
    _Pragma("unroll")                                                                    \
    for (int i = 0; i < 4; ++i) {                                                        \
      af[i][0] = *(const bf16x8*)(aR0 + (C) * 16384 + ((MH) * 64 + i * 16) * 64);        \
      af[i][1] = *(const bf16x8*)(aR1 + (C) * 16384 + ((MH) * 64 + i * 16) * 64);        \
    }                                                                                    \
  } while (0)
#define LDBv(C, NH, DST) do {                                                            \
    _Pragma("unroll")                                                                    \
    for (int j = 0; j < 2; ++j) {                                                        \
      DST[j][0] = *(const bf16x8*)(bR0 + (C) * 16384 + ((NH) * 32 + j * 16) * 64);       \
      DST[j][1] = *(const bf16x8*)(bR1 + (C) * 16384 + ((NH) * 32 + j * 16) * 64);       \
    }                                                                                    \
  } while (0)
#define MM(MH, NH, BF) do {                                                              \
    __builtin_amdgcn_s_setprio(1);                                                       \
    _Pragma("unroll")                                                                    \
    for (int ks = 0; ks < 2; ++ks)                                                       \
      _Pragma("unroll")                                                                  \
      for (int i = 0; i < 4; ++i)                                                        \
        _Pragma("unroll")                                                                \
        for (int j = 0; j < 2; ++j)                                                      \
          acc[(MH) * 4 + i][(NH) * 2 + j] =                                              \
              mfma16(af[i][ks], BF[j][ks], acc[(MH) * 4 + i][(NH) * 2 + j]);             \
    __builtin_amdgcn_s_setprio(0);                                                       \
  } while (0)

// one K-tile: TT = tile index (runtime), C = LDS buffer (compile-time 0/1)
#define TILE(TT, C) do {                                                                 \
    const int t1 = (TT) + 1, t2 = (TT) + 2;                                              \
    const bool sB = t1 < 16, sA = t2 < 16;                                               \
    /* ph0 */                                                                            \
    LDA(C, 0); LDBv(C, 0, bfA);                                                          \
    __builtin_amdgcn_sched_barrier(0);    /* pin: bfB issues AFTER af(MH0)+bfA */        \
    LDBv(C, 1, bfB);                                                                     \
    __builtin_amdgcn_sched_barrier(0);                                                   \
    if (sB) { STB(0, t1, 1 - (C)); STB(1, t1, 1 - (C)); }                                \
    asm volatile("s_waitcnt lgkmcnt(4)" ::: "memory");  /* af(MH0)+bfA done */           \
    __builtin_amdgcn_sched_barrier(0);                                                   \
    MM(0, 0, bfA);                                                                       \
    /* ph1 (af untouched: MM(0,1) still needs MH0) */                                    \
    if (sB) { STB(2, t1, 1 - (C)); STB(3, t1, 1 - (C)); }                                \
    asm volatile("s_waitcnt lgkmcnt(0)" ::: "memory");  /* bfB done (hidden) */          \
    __builtin_amdgcn_sched_barrier(0);                                                   \
    MM(0, 1, bfB);                                                                       \
    /* ph2 */                                                                            \
    LDA(C, 1);                              /* af MH1; MH0 dead after MM(0,1) */         \
    __builtin_amdgcn_sched_barrier(0);                                                   \
    asm volatile("s_waitcnt lgkmcnt(0)" ::: "memory");  /* af(MH1) done */               \
    __builtin_amdgcn_sched_barrier(0);                                                   \
    MM(1, 1, bfB);                                                                       \
    __builtin_amdgcn_s_barrier();                              /* B2 */                  \
    /* ph3 */                                                                            \
    if (sA) { STA(0, t2, C); STA(1, t2, C); STA(2, t2, C); STA(3, t2, C); }              \
    MM(1, 0, bfA);                                                                       \
    if ((TT) < 14)       asm volatile("s_waitcnt vmcnt(4)" ::: "memory");                \
    else if ((TT) == 14) asm volatile("s_waitcnt vmcnt(0)" ::: "memory");                \
    __builtin_amdgcn_s_barrier();                              /* B3 */                  \
  } while (0)

#pragma unroll
  for (int i = 0; i < 8; ++i)
#pragma unroll
    for (int j = 0; j < 4; ++j) acc[i][j] = (f32x4){0.f, 0.f, 0.f, 0.f};

  // prologue: A,B of tile 0 -> buf0; all of A of tile 1 -> buf1 (stays in flight)
  STA(0, 0, 0); STA(1, 0, 0); STA(2, 0, 0); STA(3, 0, 0);
  STB(0, 0, 0); STB(1, 0, 0); STB(2, 0, 0); STB(3, 0, 0);
  STA(0, 1, 1); STA(1, 1, 1); STA(2, 1, 1); STA(3, 1, 1);
  asm volatile("s_waitcnt vmcnt(4)" ::: "memory");
  __builtin_amdgcn_s_barrier();

#pragma unroll 1
  for (int t = 0; t < 16; t += 2) {
    bf16x8 af[4][2]; bf16x8 bfA[2][2]; bf16x8 bfB[2][2];
    TILE(t, 0);
    TILE(t + 1, 1);
  }
#undef TILE
#undef MM
#undef LDA
#undef LDBv
#undef STA
#undef STB
}

// ---------------- fused QKV GEMM: A[16384x1024] * Wqkvt[3072x1024]^T ----------------
// 256x256 tile, 512 threads, 128 KiB LDS, 1 block/CU. XCD-chunked block swizzle (768=8*96).
__global__ __launch_bounds__(512, 2) void k_gemm_qkv(
    const u16* __restrict__ A, const u16* __restrict__ Bt,
    const float* __restrict__ bq, const float* __restrict__ bk, const float* __restrict__ bv,
    u16* __restrict__ Qb, u16* __restrict__ Kb, u16* __restrict__ Vbt, float* __restrict__ sumk)
{
  __shared__ __align__(16) u16 LDS[65536];   // 128 KiB
  int lin = blockIdx.x + 12 * blockIdx.y;          // 0..767
  int nb = (lin & 7) * 96 + (lin >> 3);            // bijective XCD chunking
  const int m0 = (nb / 12) * 256, n0 = (nb % 12) * 256;
  f32x4 acc[8][4];
  gemm256_loop(A, Bt, LDS, m0, n0, acc);

  const int tid = threadIdx.x, lane = tid & 63, w = tid >> 6;
  const int wm = w >> 2, wn = w & 3;
  const int mm = lane & 15, quad = lane >> 4;
  const int sel = n0 >> 10;                   // 0=Q, 1=K, 2=V (uniform per block)
  const float* bias = sel == 0 ? bq : (sel == 1 ? bk : bv);
  // NOTE: all waves are past the loop's final barrier -> LDS free; each wave uses only
  // its own 16KB region below (no cross-wave traffic, no further barriers needed).
  u16* W = LDS + w * 8192;

  if (sel == 2) {
    // ---- V epilogue: per-wave LDS transpose, then coalesced d-major 8B stores ----
#pragma unroll
    for (int nf = 0; nf < 4; ++nf) {
      int d = nf * 16 + mm;
      float bval = bias[((n0 & 1023) + wn * 64 + nf * 16 + mm)];
#pragma unroll
      for (int mf = 0; mf < 8; ++mf) {
        int c = mf * 4 + quad;
        u16x4 pk;
        pk.x = f2bf(acc[mf][nf][0] + bval);
        pk.y = f2bf(acc[mf][nf][1] + bval);
        pk.z = f2bf(acc[mf][nf][2] + bval);
        pk.w = f2bf(acc[mf][nf][3] + bval);
        *(u16x4*)(W + d * 128 + (c ^ (d & 15)) * 4) = pk;
      }
    }
    asm volatile("s_waitcnt lgkmcnt(0)" ::: "memory");
    int h_w = ((n0 & 1023) >> 6) + wn;
    int b_ = m0 >> 12;
    int c = lane & 31, dpar = lane >> 5;
    size_t gbase = ((size_t)(b_ * 16 + h_w) * 64) * 4096 + (m0 & 4095) + wm * 128 + c * 4;
#pragma unroll
    for (int dd = 0; dd < 32; ++dd) {
      int d = dd * 2 + dpar;
      u16x4 v = *(const u16x4*)(W + d * 128 + (c ^ (d & 15)) * 4);
      *(u16x4*)(Vbt + gbase + (size_t)d * 4096) = v;
    }
    return;
  }

  // ---- Q/K epilogue: per-wave LDS re-tile [128s][64d] with chunk swizzle
  //      k(s)=(s^(s>>3))&7 (breaks the 8-way row-aliased write conflict), then
  //      16B/lane linear stores ----
  const float scl = sel == 0 ? 0.125f : 1.0f;
#pragma unroll
  for (int nf = 0; nf < 4; ++nf) {
    float bval = bias[(n0 & 1023) + wn * 64 + nf * 16 + mm];
    int d = nf * 16 + mm;
    int dc = d >> 3, dw = d & 7;
#pragma unroll
    for (int mf = 0; mf < 8; ++mf)
#pragma unroll
      for (int r = 0; r < 4; ++r) {
        int s = mf * 16 + quad * 4 + r;
        int kk = (s ^ (s >> 3)) & 7;
        W[s * 64 + ((dc ^ kk) << 3) + dw] = f2bf((acc[mf][nf][r] + bval) * scl);
      }
  }
  asm volatile("s_waitcnt lgkmcnt(0)" ::: "memory");
  {
    int h = ((n0 & 1023) >> 6) + wn;
    int mg0 = m0 + wm * 128;
    int b_ = mg0 >> 12;
    u16* dst = (sel == 0 ? Qb : Kb) + ((size_t)(b_ * 16 + h) * 4096 + (mg0 & 4095)) * 64;
    int l8 = lane >> 3, c8 = lane & 7;
#pragma unroll
    for (int i = 0; i < 16; ++i) {
      int s = i * 8 + l8;
      int kk = (l8 ^ i) & 7;
      *(bf16x8*)(dst + s * 64 + c8 * 8) = *(const bf16x8*)(W + s * 64 + ((c8 ^ kk) << 3));
    }
  }

  if (sel == 1) {
    // per-wave: wave (wm,wn) covers rows [m0+wm*128, +128) x cols [wn*64, +64)
    // -> exactly one sumk block (nb = m0/128 + wm) per wave, no cross-wave reduction.
#pragma unroll
    for (int nf = 0; nf < 4; ++nf) {
      float ssum = 0.f;
#pragma unroll
      for (int mf = 0; mf < 8; ++mf)
#pragma unroll
        for (int r = 0; r < 4; ++r) ssum += acc[mf][nf][r];
      ssum += __shfl_xor(ssum, 16);
      ssum += __shfl_xor(ssum, 32);            // sum over the 4 quads -> 128 rows
      if (quad == 0) {
        int colg = (n0 - 1024) + wn * 64 + nf * 16 + mm;
        int b_ = m0 >> 12, nb2 = ((m0 >> 7) & 31) + wm;
        sumk[(size_t)(b_ * 32 + nb2) * 1024 + colg] = ssum + 128.f * bias[colg];
      }
    }
  }
}

// ---------------- output GEMM: X[16384x1024] * Wot[1024x1024]^T + bo -> fp32 ----------------
__global__ __launch_bounds__(512, 2) void k_gemm_out(
    const u16* __restrict__ A, const u16* __restrict__ Bt,
    const float* __restrict__ bo, float* __restrict__ out)
{
  __shared__ __align__(16) u16 LDS[65536];   // 128 KiB
  int lin = blockIdx.x + 4 * blockIdx.y;           // 0..255
  int nb = (lin & 7) * 32 + (lin >> 3);            // bijective XCD chunking
  const int m0 = (nb / 4) * 256, n0 = (nb % 4) * 256;
  f32x4 acc[8][4];
  gemm256_loop(A, Bt, LDS, m0, n0, acc);

  const int tid = threadIdx.x, lane = tid & 63, w = tid >> 6;
  const int wm = w >> 2, wn = w & 3;
  const int mm = lane & 15, quad = lane >> 4;
#pragma unroll
  for (int nf = 0; nf < 4; ++nf) {
    int ng = n0 + wn * 64 + nf * 16 + mm;
    float bval = bo[ng];
#pragma unroll
    for (int mf = 0; mf < 8; ++mf)
#pragma unroll
      for (int r = 0; r < 4; ++r) {
        int mg = m0 + wm * 128 + mf * 16 + quad * 4 + r;
        out[(size_t)mg * 1024 + ng] = acc[mf][nf][r] + bval;
      }
  }
}

// ---------------- sort logits: sumk[b][n][1024] @ w_sort[1024][32] + b_sort ----------------
__global__ __launch_bounds__(256) void k_sortmm(const float* __restrict__ sumk, const float* __restrict__ wsort,
                                                const float* __restrict__ bsort, float* __restrict__ so) {
  __shared__ float red[256];
  int n = blockIdx.x, b = blockIdx.y, t = threadIdx.x;
  int m = t & 31, kp = t >> 5;
  const float* row = sumk + (size_t)(b * 32 + n) * 1024;
  float acc = 0.f;
  for (int c = kp * 128; c < kp * 128 + 128; ++c) acc += row[c] * wsort[c * 32 + m];
  red[t] = acc;
  __syncthreads();
  if (t < 32) {
    float s = bsort[t];
#pragma unroll
    for (int q = 0; q < 8; ++q) s += red[q * 32 + t];
    so[(size_t)(b * 32 + n) * 32 + t] = s;
  }
}

// ---------------- Sinkhorn (5 iters) + clip + exp ----------------
__global__ __launch_bounds__(32) void k_sinkhorn(const float* __restrict__ so, float* __restrict__ perm) {
  __shared__ float A[32][33];
  int b = blockIdx.x, t = threadIdx.x;
  for (int i = 0; i < 32; ++i) A[i][t] = so[(size_t)(b * 32 + i) * 32 + t];
  __syncthreads();
  for (int it = 0; it < 5; ++it) {
    { // row LSE (axis=2)
      float mx = -1e30f;
      for (int j = 0; j < 32; ++j) mx = fmaxf(mx, A[t][j]);
      float s = 0.f;
      for (int j = 0; j < 32; ++j) s += __expf(A[t][j] - mx);
      float l = mx + __logf(s);
      for (int j = 0; j < 32; ++j) A[t][j] -= l;
    }
    __syncthreads();
    { // col LSE (axis=1)
      float mx = -1e30f;
      for (int j = 0; j < 32; ++j) mx = fmaxf(mx, A[j][t]);
      float s = 0.f;
      for (int j = 0; j < 32; ++j) s += __expf(A[j][t] - mx);
      float l = mx + __logf(s);
      for (int j = 0; j < 32; ++j) A[j][t] -= l;
    }
    __syncthreads();
  }
  for (int i = 0; i < 32; ++i)
    perm[(size_t)(b * 32 + i) * 32 + t] = __expf(fminf(fmaxf(A[i][t], -1.f), 1.f));
}

// ---------------- merged block mix: y<16 -> K-mix (h=y), y>=16 -> V-mix (h=y-16) ----------------
__global__ __launch_bounds__(256) void k_mix(
    const u16* __restrict__ Kb, const u16* __restrict__ Vbt, const float* __restrict__ perm,
    u16* __restrict__ Ksort, u16* __restrict__ Vsort)
{
  __shared__ float P[32][32];
  int b = blockIdx.z, y = blockIdx.y, xg = blockIdx.x;
  int tid = threadIdx.x;
#pragma unroll
  for (int i = 0; i < 4; ++i) {
    int idx = i * 256 + tid;
    P[idx >> 5][idx & 31] = perm[b * 1024 + idx];
  }
  __syncthreads();
  if (y < 16) {
    // K mix: Ksort[b][h][n][128s][64d] = sum_m perm[n][m] * K[b][h][m*128+s][d]
    int h = y;
    int ss = xg * 4 + (tid >> 6), d = tid & 63;
    const u16* Kg = Kb + (size_t)(b * 16 + h) * 262144;
    float xk[32];
#pragma unroll
    for (int m = 0; m < 32; ++m) xk[m] = bf2f(Kg[(size_t)(m * 128 + ss) * 64 + d]);
    size_t tbase = (size_t)((b * 16 + h) * 32) * 8192;
#pragma unroll
    for (int nn = 0; nn < 32; ++nn) {
      float sk = 0.f;
#pragma unroll
      for (int m4 = 0; m4 < 8; ++m4) {
        float4 pv = *(const float4*)&P[nn][m4 * 4];
        sk += pv.x * xk[m4 * 4 + 0] + pv.y * xk[m4 * 4 + 1] + pv.z * xk[m4 * 4 + 2] + pv.w * xk[m4 * 4 + 3];
      }
      Ksort[tbase + (size_t)nn * 8192 + ss * 64 + d] = f2bf(sk);
    }
  } else {
    // V mix (transposed): Vsort[b][h][n][64d][128s] from Vbt[b][h][d][s]
    int h = y - 16;
    int d = xg * 2 + (tid >> 7), ss = tid & 127;
    const u16* Vg = Vbt + ((size_t)(b * 16 + h) * 64 + d) * 4096;
    float xv[32];
#pragma unroll
    for (int m = 0; m < 32; ++m) xv[m] = bf2f(Vg[m * 128 + ss]);
    size_t tbase = (size_t)((b * 16 + h) * 32) * 8192;
#pragma unroll
    for (int nn = 0; nn < 32; ++nn) {
      float sv = 0.f;
#pragma unroll
      for (int m4 = 0; m4 < 8; ++m4) {
        float4 pv = *(const float4*)&P[nn][m4 * 4];
        sv += pv.x * xv[m4 * 4 + 0] + pv.y * xv[m4 * 4 + 1] + pv.z * xv[m4 * 4 + 2] + pv.w * xv[m4 * 4 + 3];
      }
      Vsort[tbase + (size_t)nn * 8192 + d * 128 + ss] = f2bf(sv);
    }
  }
}

// ---------------- attention per (b,n,h): softmax(Q Kcat^T) Vcat ----------------
__global__ __launch_bounds__(256, 2) void k_attn(
    const u16* __restrict__ Qb, const u16* __restrict__ Kb, const u16* __restrict__ Ksort,
    const u16* __restrict__ Vbt, const u16* __restrict__ Vsort, u16* __restrict__ X)
{
  __shared__ u16 Ks[16384];    // 256 kk x 64 d (swizzled); later overlaid by per-wave P
  __shared__ u16 Vlo[8192];    // 64 d x 128 kk (orig half, swizzled)
  __shared__ u16 Vhi[8192];    // 64 d x 128 kk (sorted half, swizzled)
  int tid = threadIdx.x, lane = tid & 63, w = tid >> 6;
  int n = blockIdx.x, h = blockIdx.y, b = blockIdx.z;
  size_t bh = (size_t)(b * 16 + h);
  size_t tileK = bh * 32 + n;

  { // stage Kcat rows: [0,128) from Kb, [128,256) from Ksort. chunk = 8 rows x 64 u16.
    int l8 = lane >> 3, sl8 = lane & 7;
    const u16* Korig = Kb + (bh * 4096 + (size_t)n * 128) * 64;
    const u16* Ksrt  = Ksort + tileK * 8192;
#pragma unroll
    for (int c = 0; c < 8; ++c) {
      int cc = w * 8 + c;
      int r = cc * 8 + l8;
      int pk = sl8 ^ (r & 7);
      const u16* src = (cc < 16) ? (Korig + (size_t)r * 64 + pk * 8)
                                 : (Ksrt + (size_t)(r - 128) * 64 + pk * 8);
      gll16(src, Ks + cc * 512);
    }
    // stage V panels: chunk = 4 d-rows x 128 u16.
    int l16 = lane >> 4, sl16 = lane & 15;
    const u16* Vorig = Vbt + bh * 262144 + (size_t)n * 128;
    const u16* Vsrt  = Vsort + tileK * 8192;
#pragma unroll
    for (int c = 0; c < 4; ++c) {
      int cc = w * 4 + c;
      int d = cc * 4 + l16;
      int pv = sl16 ^ (d & 15);
      gll16(Vorig + (size_t)d * 4096 + pv * 8, Vlo + cc * 512);
      gll16(Vsrt + (size_t)d * 128 + pv * 8, Vhi + cc * 512);
    }
  }

  int mm = lane & 15, quad = lane >> 4;
  bf16x8 qf[2][2];
  {
    size_t qrow = bh * 4096 + n * 128 + w * 32;
#pragma unroll
    for (int mt = 0; mt < 2; ++mt)
#pragma unroll
      for (int ks = 0; ks < 2; ++ks)
        qf[mt][ks] = *(const bf16x8*)(Qb + (qrow + mt * 16 + mm) * 64 + ks * 32 + quad * 8);
  }
  __syncthreads();

  // S = Qs @ Kcat^T  (wave w owns q rows [w*32, w*32+32))
  f32x4 S[2][16];
#pragma unroll
  for (int mt = 0; mt < 2; ++mt)
#pragma unroll
    for (int nt = 0; nt < 16; ++nt) S[mt][nt] = (f32x4){0.f, 0.f, 0.f, 0.f};
#pragma unroll
  for (int nt = 0; nt < 16; ++nt) {
    int kk = nt * 16 + mm;
#pragma unroll
    for (int ks = 0; ks < 2; ++ks) {
      int ch = (ks * 4 + quad) ^ (kk & 7);
      bf16x8 bk = *(const bf16x8*)(Ks + kk * 64 + ch * 8);
      S[0][nt] = mfma16(qf[0][ks], bk, S[0][nt]);
      S[1][nt] = mfma16(qf[1][ks], bk, S[1][nt]);
    }
  }

  // softmax over kk (C-layout: row = quad*4+r, col = mm across nt)
  float mx[2][4], ls[2][4];
#pragma unroll
  for (int mt = 0; mt < 2; ++mt)
#pragma unroll
    for (int r = 0; r < 4; ++r) {
      float v = S[mt][0][r];
#pragma unroll
      for (int nt = 1; nt < 16; ++nt) v = fmaxf(v, S[mt][nt][r]);
#pragma unroll
      for (int o = 1; o < 16; o <<= 1) v = fmaxf(v, __shfl_xor(v, o));
      mx[mt][r] = v;
    }
#pragma unroll
  for (int mt = 0; mt < 2; ++mt)
#pragma unroll
    for (int nt = 0; nt < 16; ++nt)
#pragma unroll
      for (int r = 0; r < 4; ++r)
        S[mt][nt][r] = __expf(S[mt][nt][r] - mx[mt][r]);
#pragma unroll
  for (int mt = 0; mt < 2; ++mt)
#pragma unroll
    for (int r = 0; r < 4; ++r) {
      float s = 0.f;
#pragma unroll
      for (int nt = 0; nt < 16; ++nt) s += S[mt][nt][r];
#pragma unroll
      for (int o = 1; o < 16; o <<= 1) s += __shfl_xor(s, o);
      ls[mt][r] = s;
    }

  __syncthreads();   // all waves done reading Ks before overlaying with P

  // PV in two kk halves; P (bf16) round-trips through per-wave LDS region over Ks
  u16* Pw = Ks + w * 4096;   // 32 q-rows x 128 kk per half (8KB per wave)
  f32x4 O[2][4];
#pragma unroll
  for (int mt = 0; mt < 2; ++mt)
#pragma unroll
    for (int dt = 0; dt < 4; ++dt) O[mt][dt] = (f32x4){0.f, 0.f, 0.f, 0.f};

#pragma unroll
  for (int half = 0; half < 2; ++half) {
    const u16* Vp = half == 0 ? Vlo : Vhi;
#pragma unroll
    for (int mt = 0; mt < 2; ++mt)
#pragma unroll
      for (int nt8 = 0; nt8 < 8; ++nt8) {
        int nt = half * 8 + nt8;
        int kkl = nt8 * 16 + mm;
#pragma unroll
        for (int r = 0; r < 4; ++r) {
          int q = mt * 16 + quad * 4 + r;
          int ch = (kkl >> 3) ^ (q & 15);
          Pw[q * 128 + ch * 8 + (kkl & 7)] = f2bf(S[mt][nt][r]);
        }
      }
#pragma unroll
    for (int ksl = 0; ksl < 4; ++ksl) {
      bf16x8 pa[2];
#pragma unroll
      for (int mt = 0; mt < 2; ++mt) {
        int q = mt * 16 + mm;
        int ch = (ksl * 4 + quad) ^ (q & 15);
        pa[mt] = *(const bf16x8*)(Pw + q * 128 + ch * 8);
      }
#pragma unroll
      for (int dt = 0; dt < 4; ++dt) {
        int d = dt * 16 + mm;
        int ch = (ksl * 4 + quad) ^ (d & 15);
        bf16x8 vb = *(const bf16x8*)(Vp + d * 128 + ch * 8);
        O[0][dt] = mfma16(pa[0], vb, O[0][dt]);
        O[1][dt] = mfma16(pa[1], vb, O[1][dt]);
      }
    }
  }

  // epilogue: normalize and write X[b*4096+s][h*64+d] (bf16)
#pragma unroll
  for (int mt = 0; mt < 2; ++mt)
#pragma unroll
    for (int dt = 0; dt < 4; ++dt)
#pragma unroll
      for (int r = 0; r < 4; ++r) {
        int q = w * 32 + mt * 16 + quad * 4 + r;
        float val = O[mt][dt][r] / ls[mt][r];
        size_t row = (size_t)b * 4096 + n * 128 + q;
        X[row * 1024 + h * 64 + dt * 16 + mm] = f2bf(val);
      }
}

// ---------------- launch ----------------
extern "C" void kernel_launch(void* const* d_in, const int* in_sizes, int n_in,
                              void* d_out, int out_size, void* d_ws, size_t ws_size,
                              hipStream_t stream) {
  const float* inq   = (const float*)d_in[0];
  const float* wq    = (const float*)d_in[1];
  const float* bq    = (const float*)d_in[2];
  const float* wk    = (const float*)d_in[3];
  const float* bk    = (const float*)d_in[4];
  const float* wv    = (const float*)d_in[5];
  const float* bv    = (const float*)d_in[6];
  const float* wsort = (const float*)d_in[7];
  const float* bsort = (const float*)d_in[8];
  const float* wo    = (const float*)d_in[9];
  const float* bo    = (const float*)d_in[10];
  float* out = (float*)d_out;

  char* ws = (char*)d_ws;
  size_t off = 0;
  auto alloc = [&](size_t bytes) { char* p = ws + off; off += (bytes + 255) & ~(size_t)255; return p; };
  u16*  Qb    = (u16*)alloc(33554432);   // [4][16][4096][64] bf16, pre-scaled 1/8
  u16*  Kb    = (u16*)alloc(33554432);   // K [4][16][4096][64]
  u16*  Vbt   = (u16*)alloc(33554432);   // V transposed [4][16][64][4096]
  u16*  Ksort = (u16*)alloc(33554432);   // sorted K [4][16][32][128][64]
  u16*  Vsort = (u16*)alloc(33554432);   // sorted V^T [4][16][32][64][128]
  u16*  Abf   = (u16*)alloc(33554432);   // bf16 input; later aliased as X
  u16*  Wqkvt = (u16*)alloc(6291456);    // [3072][1024] bf16 (B^T)
  u16*  Wot   = (u16*)alloc(2097152);    // [1024][1024] bf16 (B^T)
  float* sumk = (float*)alloc(524288);   // [4][32][1024]
  float* so   = (float*)alloc(16384);    // [4][32][32]
  float* perm = (float*)alloc(16384);    // [4][32][32]
  u16*  X = Abf;   // alias: attention output over Abf (dead after k_gemm_qkv)

  k_cast<<<16384, 256, 0, stream>>>(inq, Abf);
  k_transpose4<<<dim3(32, 32, 4), dim3(32, 32), 0, stream>>>(wq, wk, wv, wo, Wqkvt, Wot);
  k_gemm_qkv<<<dim3(12, 64), 512, 0, stream>>>(Abf, Wqkvt, bq, bk, bv, Qb, Kb, Vbt, sumk);
  k_sortmm<<<dim3(32, 4), 256, 0, stream>>>(sumk, wsort, bsort, so);
  k_sinkhorn<<<4, 32, 0, stream>>>(so, perm);
  k_mix<<<dim3(32, 32, 4), 256, 0, stream>>>(Kb, Vbt, perm, Ksort, Vsort);
  k_attn<<<dim3(32, 16, 4), 256, 0, stream>>>(Qb, Kb, Ksort, Vbt, Vsort, X);
  k_gemm_out<<<dim3(4, 64), 512, 0, stream>>>(X, Wot, bo, out);
}